// Round 11
// baseline (10857.571 us; speedup 1.0000x reference)
//
#include <hip/hip_runtime.h>
#include <hip/hip_bf16.h>

typedef __attribute__((ext_vector_type(8))) short bf16x8;
typedef __attribute__((ext_vector_type(4))) float f32x4;
typedef unsigned int u32;
typedef unsigned long long u64;
typedef unsigned short u16;

__device__ __forceinline__ short f2bf(float f) {
  __hip_bfloat16 h = __float2bfloat16(f);
  return *reinterpret_cast<short*>(&h);
}
__device__ __forceinline__ float bf2f(u16 s) {
  __hip_bfloat16 h;
  *reinterpret_cast<u16*>(&h) = s;
  return __bfloat162float(h);
}
__device__ __forceinline__ float sigm(float x) { return 1.f / (1.f + __expf(-x)); }

// compiler-visible MALL-coherent load (agent-scope relaxed). hipcc tracks the
// dependency and inserts s_waitcnt before any use OR SPILL -- safe to hold the
// result in a register across another chain's phase (unlike inline-asm loads).
__device__ __forceinline__ u64 ld64a(const u16* p) {
  return __hip_atomic_load(reinterpret_cast<const u64*>(p),
                           __ATOMIC_RELAXED, __HIP_MEMORY_SCOPE_AGENT);
}
// fire-and-forget MALL store (R6-R9 proven)
__device__ __forceinline__ void st32_sys(void* p, u32 v) {
  asm volatile("global_store_dword %0, %1, off sc0 sc1"
               :: "v"((u64)(uintptr_t)p), "v"(v) : "memory");
}
__device__ __forceinline__ void vm_drain() {
  asm volatile("s_waitcnt vmcnt(0)" ::: "memory");
  __builtin_amdgcn_sched_barrier(0);
}
__device__ __forceinline__ u32 ld_flag(const u32* p) {
  return __hip_atomic_load(const_cast<u32*>(p), __ATOMIC_RELAXED, __HIP_MEMORY_SCOPE_AGENT);
}
__device__ __forceinline__ void st_flag(u32* p, u32 v) {
  __hip_atomic_store(p, v, __ATOMIC_RELAXED, __HIP_MEMORY_SCOPE_AGENT);
}
// granule ok iff all 8 bf16 LSBs match parity (pm = 0 or 0x0001000100010001)
__device__ __forceinline__ bool par2(u64 a, u64 b, u64 pm) {
  return (((a ^ pm) | (b ^ pm)) & 0x0001000100010001ull) == 0ull;
}

// ---------------- precompute kernels ----------------
__global__ void swz_generic(const float* __restrict__ src, short* __restrict__ dst,
                            int row_stride, int col_off, int nks, int nunits) {
  int uid = blockIdx.x * blockDim.x + threadIdx.x;
  if (uid >= nunits) return;
  int lane = uid & 63;
  int rem  = uid >> 6;
  int ks = rem % nks;
  int nf = rem / nks;
  int row = nf * 16 + (lane & 15);
  int k0  = col_off + ks * 32 + (lane >> 4) * 8;
  const float* s = src + (size_t)row * row_stride + k0;
  short v[8];
#pragma unroll
  for (int e = 0; e < 8; ++e) v[e] = f2bf(s[e]);
  *reinterpret_cast<int4*>(dst + (size_t)uid * 8) = *reinterpret_cast<int4*>(v);
}

__global__ void xpose_kernel(const int* __restrict__ x, int* __restrict__ xT) {
  int i = blockIdx.x * blockDim.x + threadIdx.x;   // 131072
  int b = i >> 10, t = i & 1023;
  xT[t * 128 + b] = x[i];
}

__global__ __launch_bounds__(512) void table_kernel(
    const float* __restrict__ emb, const short* __restrict__ Wx,
    const float* __restrict__ b0, float* __restrict__ table) {
  __shared__ __align__(16) char smem[65536];
  const int tid = threadIdx.x;
  const int m0 = blockIdx.x * 64;
  const int nt = blockIdx.y;
  for (int i = tid; i < 4096; i += 512) {
    int row = i >> 6, seg = i & 63;
    const float* sp = emb + (size_t)(m0 + row) * 512 + seg * 8;
    short v[8];
#pragma unroll
    for (int e = 0; e < 8; ++e) v[e] = f2bf(sp[e]);
    *reinterpret_cast<int4*>(smem + row * 1024 + ((seg * 16) ^ ((row & 7) << 4))) =
        *reinterpret_cast<int4*>(v);
  }
  __syncthreads();
  const int w = tid >> 6, lane = tid & 63, l15 = lane & 15, lq = lane >> 4;
  const int mg = (w >> 2) * 32, np = w & 3;
  const char* ap = smem + (mg + l15) * 1024;
  const int swz = (l15 & 7) << 4;
  const int nfbase = nt * 8 + np * 2;
  const short* bp0 = Wx + (size_t)nfbase * 8192 + lane * 8;
  const short* bp1 = bp0 + 8192;
  f32x4 acc[2][2] = {};
#pragma unroll 4
  for (int ks = 0; ks < 16; ++ks) {
    int kb = ks * 64 + lq * 16;
    bf16x8 a0 = *reinterpret_cast<const bf16x8*>(ap + (kb ^ swz));
    bf16x8 a1 = *reinterpret_cast<const bf16x8*>(ap + 16 * 1024 + (kb ^ swz));
    bf16x8 bv0 = *reinterpret_cast<const bf16x8*>(bp0 + ks * 512);
    bf16x8 bv1 = *reinterpret_cast<const bf16x8*>(bp1 + ks * 512);
    acc[0][0] = __builtin_amdgcn_mfma_f32_16x16x32_bf16(a0, bv0, acc[0][0], 0, 0, 0);
    acc[1][0] = __builtin_amdgcn_mfma_f32_16x16x32_bf16(a1, bv0, acc[1][0], 0, 0, 0);
    acc[0][1] = __builtin_amdgcn_mfma_f32_16x16x32_bf16(a0, bv1, acc[0][1], 0, 0, 0);
    acc[1][1] = __builtin_amdgcn_mfma_f32_16x16x32_bf16(a1, bv1, acc[1][1], 0, 0, 0);
  }
#pragma unroll
  for (int mf = 0; mf < 2; ++mf)
#pragma unroll
    for (int nfi = 0; nfi < 2; ++nfi)
#pragma unroll
      for (int r = 0; r < 4; ++r) {
        int ncol = nt * 128 + np * 32 + nfi * 16 + l15;
        int vrow = m0 + mg + mf * 16 + lq * 4 + r;
        table[(size_t)vrow * 2048 + ncol] = acc[mf][nfi][r] + b0[ncol];
      }
}

// ---------------- one chain-phase of an LSTM layer (R7 compute body) ----------------
// L0: NCOL=64, K=512 (x via table). L1: NCOL=32, K=1024.
template<int L>
__device__ __forceinline__ void lstm_phase(char* smem, int t, int bg, int cs, int tid,
    const short* bb0, const short* bb1, const float* table, const float* bias1,
    const int* __restrict__ xT, u16* h0ring, u16* h1ring, u32* FP,
    u64 (&v)[8], float& c0, float& c1, int* xids)
{
  constexpr int NCOL = (L == 0) ? 64 : 32;
  constexpr int ROWB = (L == 0) ? 1024 : 2048;
  const int w = tid >> 6, lane = tid & 63, l15 = lane & 15, lq = lane >> 4;
  const int g = w >> 1;
  const int m0 = bg * 16;
  const int myid = (L == 0) ? (128 + bg * 8 + cs) : (bg * 16 + cs);
  float* glf = reinterpret_cast<float*>(smem + ((L == 0) ? 16384 : 32768));
  const int swz = (l15 & 7) << 4;
  const bool ew = (L == 0) ? true : (tid < 256);
  const int erow = (L == 0) ? (tid >> 5) : (tid >> 4);
  const int ecp  = (L == 0) ? ((tid & 31) * 2) : ((tid & 15) * 2);
  const int esh  = ((erow >> 2) & 3) * 8;
  const int sg = tid & 63, rb = tid >> 6;

  if (L == 0 && tid < 16) xids[tid] = xT[t * 128 + m0 + tid];

  // ---- validate pre-issued loads -> bf16 XOR-swizzled LDS (parity retry) ----
  if (L == 0) {
    if (t > 0) {
      const u64 pm = (((t - 1) >> 4) & 1) ? 0x0001000100010001ull : 0ull;
      const u16* s0 = h0ring + (size_t)((t + 15) & 15) * 65536 + (size_t)m0 * 512;
      const u16* p0 = s0 + rb * 512 + sg * 8;
      const u16* p1 = s0 + (rb + 8) * 512 + sg * 8;
      int pend = 3;
      while (pend) {
        int np = 0;
        if (pend & 1) {
          if (par2(v[0], v[1], pm)) {
            ulonglong2 wv; wv.x = v[0]; wv.y = v[1];
            *reinterpret_cast<ulonglong2*>(smem + rb * 1024 + ((sg * 16) ^ ((rb & 7) << 4))) = wv;
          } else { np |= 1; v[0] = ld64a(p0); v[1] = ld64a(p0 + 4); }
        }
        if (pend & 2) {
          int r = rb + 8;
          if (par2(v[2], v[3], pm)) {
            ulonglong2 wv; wv.x = v[2]; wv.y = v[3];
            *reinterpret_cast<ulonglong2*>(smem + r * 1024 + ((sg * 16) ^ ((r & 7) << 4))) = wv;
          } else { np |= 2; v[2] = ld64a(p1); v[3] = ld64a(p1 + 4); }
        }
        pend = np;
      }
    } else {
      ulonglong2 z; z.x = 0ull; z.y = 0ull;
      *reinterpret_cast<ulonglong2*>(smem + rb * 1024 + ((sg * 16) ^ ((rb & 7) << 4))) = z;
      int r = rb + 8;
      *reinterpret_cast<ulonglong2*>(smem + r * 1024 + ((sg * 16) ^ ((r & 7) << 4))) = z;
    }
  } else {
    const u64 pm0 = ((t >> 4) & 1) ? 0x0001000100010001ull : 0ull;          // h0 epoch t
    const u64 pm1 = (((t - 1) >> 4) & 1) ? 0x0001000100010001ull : 0ull;    // h1 epoch t-1
    const u16* s0 = h0ring + (size_t)(t & 15) * 65536 + (size_t)m0 * 512;
    const u16* s1 = h1ring + (size_t)((t + 15) & 15) * 65536 + (size_t)m0 * 512;
    const u16* q0 = s0 + rb * 512 + sg * 8;
    const u16* q1 = s0 + (rb + 8) * 512 + sg * 8;
    const u16* q2 = s1 + rb * 512 + sg * 8;
    const u16* q3 = s1 + (rb + 8) * 512 + sg * 8;
    int pend;
    if (t == 0) {
      v[0] = ld64a(q0); v[1] = ld64a(q0 + 4);
      v[2] = ld64a(q1); v[3] = ld64a(q1 + 4);
      ulonglong2 z; z.x = 0ull; z.y = 0ull;
      *reinterpret_cast<ulonglong2*>(smem + rb * 2048 + ((1024 + sg * 16) ^ ((rb & 7) << 4))) = z;
      int r = rb + 8;
      *reinterpret_cast<ulonglong2*>(smem + r * 2048 + ((1024 + sg * 16) ^ ((r & 7) << 4))) = z;
      pend = 3;
    } else pend = 0xF;
    while (pend) {
      int np = 0;
      if (pend & 1) {
        if (par2(v[0], v[1], pm0)) {
          ulonglong2 wv; wv.x = v[0]; wv.y = v[1];
          *reinterpret_cast<ulonglong2*>(smem + rb * 2048 + ((sg * 16) ^ ((rb & 7) << 4))) = wv;
        } else { np |= 1; v[0] = ld64a(q0); v[1] = ld64a(q0 + 4); }
      }
      if (pend & 2) {
        int r = rb + 8;
        if (par2(v[2], v[3], pm0)) {
          ulonglong2 wv; wv.x = v[2]; wv.y = v[3];
          *reinterpret_cast<ulonglong2*>(smem + r * 2048 + ((sg * 16) ^ ((r & 7) << 4))) = wv;
        } else { np |= 2; v[2] = ld64a(q1); v[3] = ld64a(q1 + 4); }
      }
      if (pend & 4) {
        if (par2(v[4], v[5], pm1)) {
          ulonglong2 wv; wv.x = v[4]; wv.y = v[5];
          *reinterpret_cast<ulonglong2*>(smem + rb * 2048 + ((1024 + sg * 16) ^ ((rb & 7) << 4))) = wv;
        } else { np |= 4; v[4] = ld64a(q2); v[5] = ld64a(q2 + 4); }
      }
      if (pend & 8) {
        int r = rb + 8;
        if (par2(v[6], v[7], pm1)) {
          ulonglong2 wv; wv.x = v[6]; wv.y = v[7];
          *reinterpret_cast<ulonglong2*>(smem + r * 2048 + ((1024 + sg * 16) ^ ((r & 7) << 4))) = wv;
        } else { np |= 8; v[6] = ld64a(q3); v[7] = ld64a(q3 + 4); }
      }
      pend = np;
    }
  }
  __syncthreads();
  if (tid == 0) st_flag(&FP[myid * 4], (u32)(t + 1));

  // ---- bias/table prefetch ----
  float2 tbi, tbf, tbo, tbg;
  if (L == 0) {
    const float* tp = table + (size_t)xids[erow] * 2048 + cs * 64 + ecp;
    tbi = *reinterpret_cast<const float2*>(tp);
    tbf = *reinterpret_cast<const float2*>(tp + 512);
    tbo = *reinterpret_cast<const float2*>(tp + 1024);
    tbg = *reinterpret_cast<const float2*>(tp + 1536);
  } else if (ew) {
    const float* bp = bias1 + cs * 32 + ecp;
    tbi = *reinterpret_cast<const float2*>(bp);
    tbf = *reinterpret_cast<const float2*>(bp + 512);
    tbo = *reinterpret_cast<const float2*>(bp + 1024);
    tbg = *reinterpret_cast<const float2*>(bp + 1536);
  }
  // ---- MFMA ----
  const char* ap = smem + (size_t)l15 * ROWB;
  if (L == 0) {
    f32x4 a0a = {}, a0b = {}, a1a = {}, a1b = {};
#pragma unroll 4
    for (int ks = 0; ks < 16; ++ks) {
      bf16x8 a = *reinterpret_cast<const bf16x8*>(ap + ((ks * 64 + lq * 16) ^ swz));
      bf16x8 b0 = *reinterpret_cast<const bf16x8*>(bb0 + ks * 512);
      bf16x8 b1 = *reinterpret_cast<const bf16x8*>(bb1 + ks * 512);
      if (ks & 1) {
        a0b = __builtin_amdgcn_mfma_f32_16x16x32_bf16(a, b0, a0b, 0, 0, 0);
        a1b = __builtin_amdgcn_mfma_f32_16x16x32_bf16(a, b1, a1b, 0, 0, 0);
      } else {
        a0a = __builtin_amdgcn_mfma_f32_16x16x32_bf16(a, b0, a0a, 0, 0, 0);
        a1a = __builtin_amdgcn_mfma_f32_16x16x32_bf16(a, b1, a1a, 0, 0, 0);
      }
    }
    __syncthreads();
#pragma unroll
    for (int r = 0; r < 4; ++r) {
      int lrow = lq * 4 + r;
      int rot = (lrow >> 2) * 8;
      int col0 = ((w & 1) * 2) * 16 + l15;
      int col1 = ((w & 1) * 2 + 1) * 16 + l15;
      glf[(g * 16 + lrow) * 64 + ((col0 + rot) & 63)] = a0a[r] + a0b[r];
      glf[(g * 16 + lrow) * 64 + ((col1 + rot) & 63)] = a1a[r] + a1b[r];
    }
  } else {
    f32x4 acca = {}, accb = {};
#pragma unroll 4
    for (int ks = 0; ks < 32; ++ks) {
      bf16x8 a = *reinterpret_cast<const bf16x8*>(ap + ((ks * 64 + lq * 16) ^ swz));
      bf16x8 b0 = *reinterpret_cast<const bf16x8*>(bb0 + ks * 512);
      if (ks & 1) accb = __builtin_amdgcn_mfma_f32_16x16x32_bf16(a, b0, accb, 0, 0, 0);
      else        acca = __builtin_amdgcn_mfma_f32_16x16x32_bf16(a, b0, acca, 0, 0, 0);
    }
    __syncthreads();
#pragma unroll
    for (int r = 0; r < 4; ++r) {
      int lrow = lq * 4 + r;
      int col = (w & 1) * 16 + l15;
      glf[(g * 16 + lrow) * 32 + ((col + (lrow >> 2) * 8) & 31)] = acca[r] + accb[r];
    }
  }
  __syncthreads();
  // ---- elementwise: c in regs, parity-packed 4B store ----
  if (ew) {
    int cidx = (ecp + esh) & (NCOL - 1);
    float2 vi = *reinterpret_cast<float2*>(&glf[(0 * 16 + erow) * NCOL + cidx]);
    float2 vf = *reinterpret_cast<float2*>(&glf[(1 * 16 + erow) * NCOL + cidx]);
    float2 vo = *reinterpret_cast<float2*>(&glf[(2 * 16 + erow) * NCOL + cidx]);
    float2 vg = *reinterpret_cast<float2*>(&glf[(3 * 16 + erow) * NCOL + cidx]);
    float cv0 = sigm(vf.x + tbf.x) * c0 + sigm(vi.x + tbi.x) * tanhf(vg.x + tbg.x);
    float cv1 = sigm(vf.y + tbf.y) * c1 + sigm(vi.y + tbi.y) * tanhf(vg.y + tbg.y);
    c0 = cv0; c1 = cv1;
    float h0v = sigm(vo.x + tbo.x) * tanhf(cv0);
    float h1v = sigm(vo.y + tbo.y) * tanhf(cv1);
    u32 po = (u32)((t >> 4) & 1);
    u32 pk = (((u32)(u16)f2bf(h0v) & ~1u) | po)
           | ((((u32)(u16)f2bf(h1v) & ~1u) | po) << 16);
    u16* ring = (L == 0) ? h0ring : h1ring;
    size_t eo = (size_t)(t & 15) * 65536 + (size_t)(m0 + erow) * 512 + cs * NCOL + ecp;
    st32_sys(ring + eo, pk);
  }
  // ---- pre-issue next-tick loads (latency hides under the other chain's phase) ----
  if (t < 1023) {
    if (L == 0) {
      const u16* s = h0ring + (size_t)(t & 15) * 65536 + (size_t)m0 * 512;
      const u16* p0 = s + rb * 512 + sg * 8;
      const u16* p1 = s + (rb + 8) * 512 + sg * 8;
      v[0] = ld64a(p0); v[1] = ld64a(p0 + 4);
      v[2] = ld64a(p1); v[3] = ld64a(p1 + 4);
    } else {
      const u16* s0n = h0ring + (size_t)((t + 1) & 15) * 65536 + (size_t)m0 * 512;
      const u16* s1n = h1ring + (size_t)(t & 15) * 65536 + (size_t)m0 * 512;
      const u16* q0 = s0n + rb * 512 + sg * 8;
      const u16* q1 = s0n + (rb + 8) * 512 + sg * 8;
      const u16* q2 = s1n + rb * 512 + sg * 8;
      const u16* q3 = s1n + (rb + 8) * 512 + sg * 8;
      v[0] = ld64a(q0); v[1] = ld64a(q0 + 4);
      v[2] = ld64a(q1); v[3] = ld64a(q1 + 4);
      v[4] = ld64a(q2); v[5] = ld64a(q2 + 4);
      v[6] = ld64a(q3); v[7] = ld64a(q3 + 4);
    }
  }
  __syncthreads();
}

// ---------------- paired LSTM role: two independent bg chains per WG ----------------
template<int L>
__device__ void lstm_pair(char* smem, int bgA, int cs, int tid, const short* Wsw,
    const float* table, const float* bias1, const int* __restrict__ xT,
    u16* h0ring, u16* h1ring, u32* FP)
{
  constexpr int NCOL = (L == 0) ? 64 : 32;
  constexpr int NKS  = (L == 0) ? 16 : 32;
  const int bgB = bgA + 4;
  const int w = tid >> 6, lane = tid & 63;
  const int g = w >> 1;
  const int nf0 = g * 32 + cs * (NCOL / 16) + (w & 1) * ((L == 0) ? 2 : 1);
  const short* bb0 = Wsw + (size_t)nf0 * (NKS * 512) + lane * 8;
  const short* bb1 = (L == 0) ? bb0 + (size_t)(NKS * 512) : nullptr;
  int* xidsA = reinterpret_cast<int*>(smem + ((L == 0) ? 32768 : 40960));
  int* xidsB = xidsA + 16;
  u64 vA[8], vB[8];
  float cA0 = 0.f, cA1 = 0.f, cB0 = 0.f, cB1 = 0.f;

  for (int t = 0; t < 1024; ++t) {
    if (((t & 7) == 0) && t >= 16) {
      if (w == 0) {
        const u32* a = nullptr;
        if (L == 0) {
          if (lane < 16)      a = &FP[(bgA * 16 + lane) * 4];
          else if (lane < 24) a = &FP[(128 + bgA * 8 + lane - 16) * 4];
          else if (lane < 40) a = &FP[(bgB * 16 + (lane - 24)) * 4];
          else if (lane < 48) a = &FP[(128 + bgB * 8 + (lane - 40)) * 4];
        } else {
          if (lane < 16)       a = &FP[(bgA * 16 + lane) * 4];
          else if (lane == 16) a = &FP[(192 + bgA) * 4];
          else if (lane >= 24 && lane < 40) a = &FP[(bgB * 16 + (lane - 24)) * 4];
          else if (lane == 40) a = &FP[(192 + bgB) * 4];
        }
        if (a) { u32 tgt = (u32)(t - 6); while (ld_flag(a) < tgt) __builtin_amdgcn_s_sleep(1); }
      }
      __syncthreads();
    }
    lstm_phase<L>(smem, t, bgA, cs, tid, bb0, bb1, table, bias1, xT,
                  h0ring, h1ring, FP, vA, cA0, cA1, xidsA);
    lstm_phase<L>(smem, t, bgB, cs, tid, bb0, bb1, table, bias1, xT,
                  h0ring, h1ring, FP, vB, cB0, cB1, xidsB);
  }
  vm_drain();
}

// ---------------- projection: one chain-phase ----------------
__device__ __forceinline__ void proj_phase(char* smem, int t, int bg, int tid,
    const u16* h1ring, u32* FP, const short* bp0, const short* bp1,
    const float* lng, const float* lnb, float pb0, float pb1,
    float* out, u64 (&v)[4])
{
  const int w = tid >> 6, lane = tid & 63, l15 = lane & 15, lq = lane >> 4;
  const int m0 = bg * 16;
  const int swzrow = (l15 & 7) << 4;
  const int sg = tid & 63, rb = tid >> 6;
  {
    const u64 pm = ((t >> 4) & 1) ? 0x0001000100010001ull : 0ull;
    const u16* src = h1ring + (size_t)(t & 15) * 65536 + (size_t)m0 * 512;
    const u16* p0 = src + rb * 512 + sg * 8;
    const u16* p1 = src + (rb + 8) * 512 + sg * 8;
    int pend = 3;
    while (pend) {
      int np = 0;
      if (pend & 1) {
        if (par2(v[0], v[1], pm)) {
          ulonglong2 wv; wv.x = v[0]; wv.y = v[1];
          *reinterpret_cast<ulonglong2*>(smem + rb * 1024 + sg * 16) = wv;
        } else { np |= 1; v[0] = ld64a(p0); v[1] = ld64a(p0 + 4); }
      }
      if (pend & 2) {
        int r = rb + 8;
        if (par2(v[2], v[3], pm)) {
          ulonglong2 wv; wv.x = v[2]; wv.y = v[3];
          *reinterpret_cast<ulonglong2*>(smem + r * 1024 + sg * 16) = wv;
        } else { np |= 2; v[2] = ld64a(p1); v[3] = ld64a(p1 + 4); }
      }
      pend = np;
    }
  }
  __syncthreads();
  if (tid == 0) st_flag(&FP[(192 + bg) * 4], (u32)(t + 1));
  {
    int row = tid >> 5, j = tid & 31;
    const u16* hr = reinterpret_cast<const u16*>(smem) + row * 512;
    float s1 = 0.f, s2 = 0.f;
#pragma unroll
    for (int kk = 0; kk < 16; ++kk) {
      float vv = bf2f(hr[j + kk * 32]);
      s1 += vv; s2 += vv * vv;
    }
#pragma unroll
    for (int d = 1; d < 32; d <<= 1) { s1 += __shfl_xor(s1, d, 32); s2 += __shfl_xor(s2, d, 32); }
    float mu = s1 * (1.f / 512.f);
    float rs = rsqrtf(s2 * (1.f / 512.f) - mu * mu + 1e-5f);
    char* zn = smem + 16384;
#pragma unroll
    for (int kk = 0; kk < 16; ++kk) {
      int kcol = j + kk * 32;
      float vv = bf2f(hr[kcol]);
      float nv = (vv - mu) * rs * lng[kcol] + lnb[kcol];
      *reinterpret_cast<short*>(zn + row * 1024 + ((kcol * 2) ^ ((row & 7) << 4))) = f2bf(nv);
    }
  }
  __syncthreads();
  const char* ap = smem + 16384 + (size_t)l15 * 1024;
  f32x4 acc[2][2] = {};
#pragma unroll 4
  for (int ks = 0; ks < 16; ++ks) {
    bf16x8 a = *reinterpret_cast<const bf16x8*>(ap + ((ks * 64 + lq * 16) ^ swzrow));
    bf16x8 b0 = *reinterpret_cast<const bf16x8*>(bp0 + ks * 512);
    bf16x8 b1 = *reinterpret_cast<const bf16x8*>(bp1 + ks * 512);
    acc[0][ks & 1] = __builtin_amdgcn_mfma_f32_16x16x32_bf16(a, b0, acc[0][ks & 1], 0, 0, 0);
    acc[1][ks & 1] = __builtin_amdgcn_mfma_f32_16x16x32_bf16(a, b1, acc[1][ks & 1], 0, 0, 0);
  }
#pragma unroll
  for (int nfi = 0; nfi < 2; ++nfi) {
    int vcol = (w * 2 + nfi) * 16 + l15;
    float pbv = nfi ? pb1 : pb0;
#pragma unroll
    for (int r = 0; r < 4; ++r) {
      float vv = acc[nfi][0][r] + acc[nfi][1][r] + pbv;
      out[(size_t)(m0 + lq * 4 + r) * 262144 + (size_t)t * 256 + vcol] = vv;
    }
  }
  __syncthreads();
}

__device__ void proj_pair(char* smem, int bgA, int tid, const u16* h1ring, u32* FP,
    const short* pWswz, const float* lng, const float* lnb, const float* pb, float* out)
{
  const int bgB = bgA + 4;
  const int w = tid >> 6, lane = tid & 63, l15 = lane & 15;
  const short* bp0 = pWswz + (size_t)(w * 2) * 8192 + lane * 8;
  const short* bp1 = bp0 + 8192;
  float pb0 = pb[(w * 2) * 16 + l15], pb1 = pb[(w * 2 + 1) * 16 + l15];
  const int sg = tid & 63, rb = tid >> 6;
  u64 vA[4], vB[4];

  for (int t = 0; t < 1024; ++t) {
    const u16* sA = h1ring + (size_t)(t & 15) * 65536 + (size_t)(bgA * 16) * 512;
    const u16* sB = h1ring + (size_t)(t & 15) * 65536 + (size_t)(bgB * 16) * 512;
    vA[0] = ld64a(sA + rb * 512 + sg * 8);       vA[1] = ld64a(sA + rb * 512 + sg * 8 + 4);
    vA[2] = ld64a(sA + (rb + 8) * 512 + sg * 8); vA[3] = ld64a(sA + (rb + 8) * 512 + sg * 8 + 4);
    vB[0] = ld64a(sB + rb * 512 + sg * 8);       vB[1] = ld64a(sB + rb * 512 + sg * 8 + 4);
    vB[2] = ld64a(sB + (rb + 8) * 512 + sg * 8); vB[3] = ld64a(sB + (rb + 8) * 512 + sg * 8 + 4);
    proj_phase(smem, t, bgA, tid, h1ring, FP, bp0, bp1, lng, lnb, pb0, pb1, out, vA);
    proj_phase(smem, t, bgB, tid, h1ring, FP, bp0, bp1, lng, lnb, pb0, pb1, out, vB);
  }
  vm_drain();
}

// Grid: 100 blocks. 0..63 = L1 (pair=bid>>4, cs=bid&15), 64..95 = L0 (pair, cs),
// 96..99 = proj pair. Each WG interleaves chains bg=pair and bg=pair+4.
__global__ __launch_bounds__(512, 1) void persist_kernel(
    const short* __restrict__ W0h, const short* __restrict__ W1,
    const float* __restrict__ table, const float* __restrict__ bias1,
    const int* __restrict__ xT,
    u16* __restrict__ h0ring, u16* __restrict__ h1ring, u32* __restrict__ flags,
    const short* __restrict__ pWswz, const float* __restrict__ lng,
    const float* __restrict__ lnb, const float* __restrict__ pb, float* __restrict__ out)
{
  __shared__ __align__(16) char smem[49408];
  const int bid = blockIdx.x, tid = threadIdx.x;
  if (bid < 64) {
    lstm_pair<1>(smem, bid >> 4, bid & 15, tid, W1, nullptr, bias1, xT,
                 h0ring, h1ring, flags);
  } else if (bid < 96) {
    int idx = bid - 64;
    lstm_pair<0>(smem, idx >> 3, idx & 7, tid, W0h, table, nullptr, xT,
                 h0ring, h1ring, flags);
  } else {
    proj_pair(smem, bid - 96, tid, h1ring, flags, pWswz, lng, lnb, pb, out);
  }
}

extern "C" void kernel_launch(void* const* d_in, const int* in_sizes, int n_in,
                              void* d_out, int out_size, void* d_ws, size_t ws_size,
                              hipStream_t stream) {
  const int*   x    = (const int*)d_in[0];
  const float* emb  = (const float*)d_in[1];
  const float* W    = (const float*)d_in[2];
  const float* bias = (const float*)d_in[3];
  const float* lng  = (const float*)d_in[4];
  const float* lnb  = (const float*)d_in[5];
  const float* pW   = (const float*)d_in[6];
  const float* pb   = (const float*)d_in[7];
  float* out = (float*)d_out;

  char* ws = (char*)d_ws;
  short* W0h   = (short*)(ws + 0);           // 2 MB
  short* W1sw  = (short*)(ws + 2097152);     // 4 MB
  short* pWsw  = (short*)(ws + 6291456);     // 256 KB
  float* table = (float*)(ws + 6815744);     // 2 MB
  int*   xT    = (int*)(ws + 8912896);       // 512 KB
  u32*   flags = (u32*)(ws + 9437184);       // 4 KB (prog)
  u16*   h0ring= (u16*)(ws + 9961472);       // 2 MB: 16 x [128][512] bf16 (parity LSB)
  u16*   h1ring= (u16*)(ws + 12058624);      // 2 MB
  short* W0x   = (short*)(ws + 14155776);    // 2 MB temp (table build)

  swz_generic<<<dim3(512), dim3(256), 0, stream>>>(W, W0h, 1024, 512, 16, 131072);
  swz_generic<<<dim3(1024), dim3(256), 0, stream>>>(W + 2048 * 1024, W1sw, 1024, 0, 32, 262144);
  swz_generic<<<dim3(64), dim3(256), 0, stream>>>(pW, pWsw, 512, 0, 16, 16384);
  xpose_kernel<<<dim3(512), dim3(256), 0, stream>>>(x, xT);
  swz_generic<<<dim3(512), dim3(256), 0, stream>>>(W, W0x, 1024, 0, 16, 131072);
  table_kernel<<<dim3(4, 16), dim3(512), 0, stream>>>(emb, W0x, bias, table);
  hipMemsetAsync(ws + 9437184, 0, 4096, stream);          // prog flags
  hipMemsetAsync(ws + 9961472, 0x01, 4194304, stream);    // rings: parity-reject init

  persist_kernel<<<dim3(100), dim3(512), 0, stream>>>(
      W0h, W1sw, table, bias + 2048, xT, h0ring, h1ring, flags,
      pWsw, lng, lnb, pb, out);
}

// Round 12
// 5010.033 us; speedup vs baseline: 2.1672x; 2.1672x over previous
//
#include <hip/hip_runtime.h>
#include <hip/hip_bf16.h>

typedef __attribute__((ext_vector_type(8))) short bf16x8;
typedef __attribute__((ext_vector_type(4))) float f32x4;
typedef __attribute__((ext_vector_type(4))) unsigned int u32x4;
typedef unsigned int u32;
typedef unsigned long long u64;
typedef unsigned short u16;

__device__ __forceinline__ short f2bf(float f) {
  __hip_bfloat16 h = __float2bfloat16(f);
  return *reinterpret_cast<short*>(&h);
}
__device__ __forceinline__ float bf2f(u16 s) {
  __hip_bfloat16 h;
  *reinterpret_cast<u16*>(&h) = s;
  return __bfloat162float(h);
}
__device__ __forceinline__ float sigm(float x) { return 1.f / (1.f + __expf(-x)); }

// ---- MALL-coherent transport (R7-proven) ----
__device__ __forceinline__ u32x4 ld128_sys(const void* p) {
  u32x4 r;
  asm volatile("global_load_dwordx4 %0, %1, off sc0 sc1"
               : "=v"(r) : "v"((u64)(uintptr_t)p) : "memory");
  return r;
}
__device__ __forceinline__ void st32_sys(void* p, u32 v) {
  asm volatile("global_store_dword %0, %1, off sc0 sc1"
               :: "v"((u64)(uintptr_t)p), "v"(v) : "memory");
}
__device__ __forceinline__ void vm_drain() {
  asm volatile("s_waitcnt vmcnt(0)" ::: "memory");
  __builtin_amdgcn_sched_barrier(0);
}
__device__ __forceinline__ void vm_wait2() {
  asm volatile("s_waitcnt vmcnt(2)" ::: "memory");
  __builtin_amdgcn_sched_barrier(0);
}
__device__ __forceinline__ u32 ld_flag(const u32* p) {
  return __hip_atomic_load(const_cast<u32*>(p), __ATOMIC_RELAXED, __HIP_MEMORY_SCOPE_AGENT);
}
__device__ __forceinline__ void st_flag(u32* p, u32 v) {
  __hip_atomic_store(p, v, __ATOMIC_RELAXED, __HIP_MEMORY_SCOPE_AGENT);
}
// parity check: all 8 bf16 LSBs in a 16B granule == p?  (pm = p ? 0x00010001 : 0)
__device__ __forceinline__ bool par_ok(u32x4 v, u32 pm) {
  u32 z = ((v[0] ^ pm) | (v[1] ^ pm) | (v[2] ^ pm) | (v[3] ^ pm)) & 0x00010001u;
  return z == 0;
}

// ---------------- precompute kernels ----------------
__global__ void swz_generic(const float* __restrict__ src, short* __restrict__ dst,
                            int row_stride, int col_off, int nks, int nunits) {
  int uid = blockIdx.x * blockDim.x + threadIdx.x;
  if (uid >= nunits) return;
  int lane = uid & 63;
  int rem  = uid >> 6;
  int ks = rem % nks;
  int nf = rem / nks;
  int row = nf * 16 + (lane & 15);
  int k0  = col_off + ks * 32 + (lane >> 4) * 8;
  const float* s = src + (size_t)row * row_stride + k0;
  short v[8];
#pragma unroll
  for (int e = 0; e < 8; ++e) v[e] = f2bf(s[e]);
  *reinterpret_cast<int4*>(dst + (size_t)uid * 8) = *reinterpret_cast<int4*>(v);
}

__global__ void xpose_kernel(const int* __restrict__ x, int* __restrict__ xT) {
  int i = blockIdx.x * blockDim.x + threadIdx.x;   // 131072
  int b = i >> 10, t = i & 1023;
  xT[t * 128 + b] = x[i];
}

__global__ __launch_bounds__(512) void table_kernel(
    const float* __restrict__ emb, const short* __restrict__ Wx,
    const float* __restrict__ b0, float* __restrict__ table) {
  __shared__ __align__(16) char smem[65536];
  const int tid = threadIdx.x;
  const int m0 = blockIdx.x * 64;
  const int nt = blockIdx.y;
  for (int i = tid; i < 4096; i += 512) {
    int row = i >> 6, seg = i & 63;
    const float* sp = emb + (size_t)(m0 + row) * 512 + seg * 8;
    short v[8];
#pragma unroll
    for (int e = 0; e < 8; ++e) v[e] = f2bf(sp[e]);
    *reinterpret_cast<int4*>(smem + row * 1024 + ((seg * 16) ^ ((row & 7) << 4))) =
        *reinterpret_cast<int4*>(v);
  }
  __syncthreads();
  const int w = tid >> 6, lane = tid & 63, l15 = lane & 15, lq = lane >> 4;
  const int mg = (w >> 2) * 32, np = w & 3;
  const char* ap = smem + (mg + l15) * 1024;
  const int swz = (l15 & 7) << 4;
  const int nfbase = nt * 8 + np * 2;
  const short* bp0 = Wx + (size_t)nfbase * 8192 + lane * 8;
  const short* bp1 = bp0 + 8192;
  f32x4 acc[2][2] = {};
#pragma unroll 4
  for (int ks = 0; ks < 16; ++ks) {
    int kb = ks * 64 + lq * 16;
    bf16x8 a0 = *reinterpret_cast<const bf16x8*>(ap + (kb ^ swz));
    bf16x8 a1 = *reinterpret_cast<const bf16x8*>(ap + 16 * 1024 + (kb ^ swz));
    bf16x8 bv0 = *reinterpret_cast<const bf16x8*>(bp0 + ks * 512);
    bf16x8 bv1 = *reinterpret_cast<const bf16x8*>(bp1 + ks * 512);
    acc[0][0] = __builtin_amdgcn_mfma_f32_16x16x32_bf16(a0, bv0, acc[0][0], 0, 0, 0);
    acc[1][0] = __builtin_amdgcn_mfma_f32_16x16x32_bf16(a1, bv0, acc[1][0], 0, 0, 0);
    acc[0][1] = __builtin_amdgcn_mfma_f32_16x16x32_bf16(a0, bv1, acc[0][1], 0, 0, 0);
    acc[1][1] = __builtin_amdgcn_mfma_f32_16x16x32_bf16(a1, bv1, acc[1][1], 0, 0, 0);
  }
#pragma unroll
  for (int mf = 0; mf < 2; ++mf)
#pragma unroll
    for (int nfi = 0; nfi < 2; ++nfi)
#pragma unroll
      for (int r = 0; r < 4; ++r) {
        int ncol = nt * 128 + np * 32 + nfi * 16 + l15;
        int vrow = m0 + mg + mf * 16 + lq * 4 + r;
        table[(size_t)vrow * 2048 + ncol] = acc[mf][nfi][r] + b0[ncol];
      }
}

// ---------------- LSTM role (M_wg = 16 rows) ----------------
template<int L>
__device__ void lstm_role(char* smem, int bg, int cs, int tid,
    const short* __restrict__ Wsw, const float* __restrict__ table,
    const float* __restrict__ bias1, const int* __restrict__ xT,
    u16* __restrict__ h0ring, u16* __restrict__ h1ring, u32* __restrict__ FP)
{
  constexpr int NCOL = (L == 0) ? 64 : 32;
  constexpr int NKS  = (L == 0) ? 16 : 32;
  constexpr int ROWB = (L == 0) ? 1024 : 2048;
  const int w = tid >> 6, lane = tid & 63, l15 = lane & 15, lq = lane >> 4;
  const int g = w >> 1;
  const int m0 = bg * 16;
  const int myid = (L == 0) ? (128 + bg * 8 + cs) : (bg * 16 + cs);
  const int nf0 = g * 32 + cs * (NCOL / 16) + (w & 1) * ((L == 0) ? 2 : 1);
  const short* bb0 = Wsw + (size_t)nf0 * (NKS * 512) + lane * 8;
  const short* bb1 = (L == 0) ? bb0 + (size_t)(NKS * 512) : nullptr;
  float* glf = reinterpret_cast<float*>(smem + ((L == 0) ? 16384 : 32768));
  int* xids = reinterpret_cast<int*>(smem + ((L == 0) ? 32768 : 40960));
  const int swz = (l15 & 7) << 4;
  const bool ew = (L == 0) ? true : (tid < 256);
  const int erow = (L == 0) ? (tid >> 5) : (tid >> 4);
  const int ecp  = (L == 0) ? ((tid & 31) * 2) : ((tid & 15) * 2);
  const int esh  = ((erow >> 2) & 3) * 8;          // gate-exchange rotation
  float c0 = 0.f, c1 = 0.f;
  float2 breg[4];
  if (L == 1 && ew) {
#pragma unroll
    for (int gg = 0; gg < 4; ++gg)
      breg[gg] = *reinterpret_cast<const float2*>(bias1 + gg * 512 + cs * 32 + ecp);
  }
  const int sg = tid & 63;

  for (int t = 0; t < 1024; ++t) {
    // ---- backpressure (every 8 ticks, FP only) ----
    if (((t & 7) == 0) && t >= 16) {
      if (w == 0) {
        const u32* a = nullptr;
        if (L == 0) {
          if (lane < 16)      a = &FP[(bg * 16 + lane) * 4];          // L1 consumers of h0
          else if (lane < 24) a = &FP[(128 + bg * 8 + lane - 16) * 4];// L0 peers
        } else {
          if (lane < 16)      a = &FP[(bg * 16 + lane) * 4];          // L1 peers
          else if (lane == 16) a = &FP[(192 + bg) * 4];               // proj
        }
        if (a) { u32 tgt = (u32)(t - 6); while (ld_flag(a) < tgt) __builtin_amdgcn_s_sleep(1); }
      }
    }
    if (L == 0 && tid < 16) xids[tid] = xT[t * 128 + m0 + tid];
    // (no barrier here: xids is read only after the post-staging barrier; the
    //  poll result is only needed before the ew store, fenced by later barriers)

    if (L == 0) {
      // ---- stage h0(t-1): parity-validated retry -> bf16 XOR-swizzled LDS ----
      const u32 pm = (((t - 1) >> 4) & 1) ? 0x00010001u : 0u;
      const u16* s0 = h0ring + (size_t)((t + 15) & 15) * 65536 + (size_t)m0 * 512;
      u32x4 v[2];
      const int r0 = tid >> 6, r1 = r0 + 8;
      if (t > 0) {
        v[0] = ld128_sys(s0 + r0 * 512 + sg * 8);
        v[1] = ld128_sys(s0 + r1 * 512 + sg * 8);
        int pend = 3;
        while (pend) {
          vm_drain();
          int np = 0;
          if (pend & 1) {
            if (par_ok(v[0], pm))
              *reinterpret_cast<u32x4*>(smem + r0 * 1024 + ((sg * 16) ^ ((r0 & 7) << 4))) = v[0];
            else { np |= 1; v[0] = ld128_sys(s0 + r0 * 512 + sg * 8); }
          }
          if (pend & 2) {
            if (par_ok(v[1], pm))
              *reinterpret_cast<u32x4*>(smem + r1 * 1024 + ((sg * 16) ^ ((r1 & 7) << 4))) = v[1];
            else { np |= 2; v[1] = ld128_sys(s0 + r1 * 512 + sg * 8); }
          }
          pend = np;
        }
      } else {
        u32x4 z = {0, 0, 0, 0};
        *reinterpret_cast<u32x4*>(smem + r0 * 1024 + ((sg * 16) ^ ((r0 & 7) << 4))) = z;
        *reinterpret_cast<u32x4*>(smem + r1 * 1024 + ((sg * 16) ^ ((r1 & 7) << 4))) = z;
      }
      __syncthreads();                                   // S2: staging ready
      if (tid == 0) st_flag(&FP[myid * 4], (u32)(t + 1));
      // table prefetch (overlaps MFMA)
      const float* tp = table + (size_t)xids[erow] * 2048 + cs * 64 + ecp;
      float2 tbi = *reinterpret_cast<const float2*>(tp);
      float2 tbf = *reinterpret_cast<const float2*>(tp + 512);
      float2 tbo = *reinterpret_cast<const float2*>(tp + 1024);
      float2 tbg = *reinterpret_cast<const float2*>(tp + 1536);
      // ---- MFMA ----
      const char* ap = smem + (size_t)l15 * ROWB;
      f32x4 acc[2][2] = {};
#pragma unroll 4
      for (int ks = 0; ks < NKS; ++ks) {
        bf16x8 a = *reinterpret_cast<const bf16x8*>(ap + ((ks * 64 + lq * 16) ^ swz));
        bf16x8 b0 = *reinterpret_cast<const bf16x8*>(bb0 + ks * 512);
        bf16x8 b1 = *reinterpret_cast<const bf16x8*>(bb1 + ks * 512);
        acc[0][ks & 1] = __builtin_amdgcn_mfma_f32_16x16x32_bf16(a, b0, acc[0][ks & 1], 0, 0, 0);
        acc[1][ks & 1] = __builtin_amdgcn_mfma_f32_16x16x32_bf16(a, b1, acc[1][ks & 1], 0, 0, 0);
      }
      // (no barrier: glf [16K,32K) does not alias staging [0,16K); prior-tick
      //  glf reads are fenced by the loop-end barrier)
#pragma unroll
      for (int nfi = 0; nfi < 2; ++nfi) {
        int col = ((w & 1) * 2 + nfi) * 16 + l15;
#pragma unroll
        for (int r = 0; r < 4; ++r) {
          int lrow = lq * 4 + r;
          glf[(g * 16 + lrow) * 64 + ((col + (lrow >> 2) * 8) & 63)] =
              acc[nfi][0][r] + acc[nfi][1][r];
        }
      }
      __syncthreads();                                   // S4: exchange ready
      // ---- elementwise ----
      int cidx = (ecp + esh) & 63;
      float2 vi = *reinterpret_cast<float2*>(&glf[(0 * 16 + erow) * 64 + cidx]);
      float2 vf = *reinterpret_cast<float2*>(&glf[(1 * 16 + erow) * 64 + cidx]);
      float2 vo = *reinterpret_cast<float2*>(&glf[(2 * 16 + erow) * 64 + cidx]);
      float2 vg = *reinterpret_cast<float2*>(&glf[(3 * 16 + erow) * 64 + cidx]);
      float cv0 = sigm(vf.x + tbf.x) * c0 + sigm(vi.x + tbi.x) * tanhf(vg.x + tbg.x);
      float cv1 = sigm(vf.y + tbf.y) * c1 + sigm(vi.y + tbi.y) * tanhf(vg.y + tbg.y);
      c0 = cv0; c1 = cv1;
      float h0v = sigm(vo.x + tbo.x) * tanhf(cv0);
      float h1v = sigm(vo.y + tbo.y) * tanhf(cv1);
      u32 po = (u32)((t >> 4) & 1);
      u32 pk = (((u32)(u16)f2bf(h0v) & ~1u) | po)
             | ((((u32)(u16)f2bf(h1v) & ~1u) | po) << 16);
      size_t eo = (size_t)(t & 15) * 65536 + (size_t)(m0 + erow) * 512 + cs * 64 + ecp;
      st32_sys(h0ring + eo, pk);
      __syncthreads();                                   // S5: loop end
    } else {
      // ---- L1: issue h0 then h1; validate h0 (old, visible) first, compute
      //      h0-half MFMAs while h1 stores gain visibility time ----
      const u32 pm0 = ((t >> 4) & 1) ? 0x00010001u : 0u;         // h0 epoch t
      const u32 pm1 = (((t - 1) >> 4) & 1) ? 0x00010001u : 0u;   // h1 epoch t-1
      const u16* s0 = h0ring + (size_t)(t & 15) * 65536 + (size_t)m0 * 512;
      const u16* s1 = h1ring + (size_t)((t + 15) & 15) * 65536 + (size_t)m0 * 512;
      const int r0 = tid >> 6, r1 = r0 + 8;   // rows within the 16-row group
      u32x4 v[4];
      v[0] = ld128_sys(s0 + r0 * 512 + sg * 8);
      v[1] = ld128_sys(s0 + r1 * 512 + sg * 8);
      if (t > 0) {
        v[2] = ld128_sys(s1 + r0 * 512 + sg * 8);
        v[3] = ld128_sys(s1 + r1 * 512 + sg * 8);
      } else {
        u32x4 z = {0, 0, 0, 0};
        *reinterpret_cast<u32x4*>(smem + r0 * 2048 + ((1024 + sg * 16) ^ ((r0 & 7) << 4))) = z;
        *reinterpret_cast<u32x4*>(smem + r1 * 2048 + ((1024 + sg * 16) ^ ((r1 & 7) << 4))) = z;
      }
      // wait only for the h0 granules (last 2 issued may stay in flight)
      if (t > 0) vm_wait2(); else vm_drain();
      {
        int pend = 0;
        if (par_ok(v[0], pm0))
          *reinterpret_cast<u32x4*>(smem + r0 * 2048 + ((sg * 16) ^ ((r0 & 7) << 4))) = v[0];
        else pend |= 1;
        if (par_ok(v[1], pm0))
          *reinterpret_cast<u32x4*>(smem + r1 * 2048 + ((sg * 16) ^ ((r1 & 7) << 4))) = v[1];
        else pend |= 2;
        while (pend) {
          if (pend & 1) v[0] = ld128_sys(s0 + r0 * 512 + sg * 8);
          if (pend & 2) v[1] = ld128_sys(s0 + r1 * 512 + sg * 8);
          vm_drain();
          int np = 0;
          if (pend & 1) {
            if (par_ok(v[0], pm0))
              *reinterpret_cast<u32x4*>(smem + r0 * 2048 + ((sg * 16) ^ ((r0 & 7) << 4))) = v[0];
            else np |= 1;
          }
          if (pend & 2) {
            if (par_ok(v[1], pm0))
              *reinterpret_cast<u32x4*>(smem + r1 * 2048 + ((sg * 16) ^ ((r1 & 7) << 4))) = v[1];
            else np |= 2;
          }
          pend = np;
        }
      }
      __syncthreads();                                   // S2a: h0 staged
      // ---- MFMA h0-half (ks 0..15) while h1 loads settle ----
      const char* ap = smem + (size_t)l15 * ROWB;
      f32x4 acca = {}, accb = {};
#pragma unroll 4
      for (int ks = 0; ks < 16; ++ks) {
        bf16x8 a = *reinterpret_cast<const bf16x8*>(ap + ((ks * 64 + lq * 16) ^ swz));
        bf16x8 b0 = *reinterpret_cast<const bf16x8*>(bb0 + ks * 512);
        if (ks & 1) accb = __builtin_amdgcn_mfma_f32_16x16x32_bf16(a, b0, accb, 0, 0, 0);
        else        acca = __builtin_amdgcn_mfma_f32_16x16x32_bf16(a, b0, acca, 0, 0, 0);
      }
      // ---- validate h1 (t-1) ----
      if (t > 0) {
        int pend = 0xC;
        while (pend) {
          vm_drain();
          int np = 0;
          if (pend & 4) {
            if (par_ok(v[2], pm1))
              *reinterpret_cast<u32x4*>(smem + r0 * 2048 + ((1024 + sg * 16) ^ ((r0 & 7) << 4))) = v[2];
            else { np |= 4; v[2] = ld128_sys(s1 + r0 * 512 + sg * 8); }
          }
          if (pend & 8) {
            if (par_ok(v[3], pm1))
              *reinterpret_cast<u32x4*>(smem + r1 * 2048 + ((1024 + sg * 16) ^ ((r1 & 7) << 4))) = v[3];
            else { np |= 8; v[3] = ld128_sys(s1 + r1 * 512 + sg * 8); }
          }
          pend = np;
        }
      }
      __syncthreads();                                   // S2b: h1 staged
      if (tid == 0) st_flag(&FP[myid * 4], (u32)(t + 1));
      // ---- MFMA h1-half (ks 16..31) ----
#pragma unroll 4
      for (int ks = 16; ks < 32; ++ks) {
        bf16x8 a = *reinterpret_cast<const bf16x8*>(ap + ((ks * 64 + lq * 16) ^ swz));
        bf16x8 b0 = *reinterpret_cast<const bf16x8*>(bb0 + ks * 512);
        if (ks & 1) accb = __builtin_amdgcn_mfma_f32_16x16x32_bf16(a, b0, accb, 0, 0, 0);
        else        acca = __builtin_amdgcn_mfma_f32_16x16x32_bf16(a, b0, acca, 0, 0, 0);
      }
      // (no barrier: glf [32K,41K) does not alias staging [0,32K))
      {
        int col = (w & 1) * 16 + l15;
#pragma unroll
        for (int r = 0; r < 4; ++r) {
          int lrow = lq * 4 + r;
          glf[(g * 16 + lrow) * 32 + ((col + (lrow >> 2) * 8) & 31)] = acca[r] + accb[r];
        }
      }
      __syncthreads();                                   // S4: exchange ready
      if (ew) {
        int cidx = (ecp + esh) & 31;
        float2 vi = *reinterpret_cast<float2*>(&glf[(0 * 16 + erow) * 32 + cidx]);
        float2 vf = *reinterpret_cast<float2*>(&glf[(1 * 16 + erow) * 32 + cidx]);
        float2 vo = *reinterpret_cast<float2*>(&glf[(2 * 16 + erow) * 32 + cidx]);
        float2 vg = *reinterpret_cast<float2*>(&glf[(3 * 16 + erow) * 32 + cidx]);
        float cv0 = sigm(vf.x + breg[1].x) * c0 + sigm(vi.x + breg[0].x) * tanhf(vg.x + breg[3].x);
        float cv1 = sigm(vf.y + breg[1].y) * c1 + sigm(vi.y + breg[0].y) * tanhf(vg.y + breg[3].y);
        c0 = cv0; c1 = cv1;
        float h0v = sigm(vo.x + breg[2].x) * tanhf(cv0);
        float h1v = sigm(vo.y + breg[2].y) * tanhf(cv1);
        u32 po = (u32)((t >> 4) & 1);
        u32 pk = (((u32)(u16)f2bf(h0v) & ~1u) | po)
               | ((((u32)(u16)f2bf(h1v) & ~1u) | po) << 16);
        size_t eo = (size_t)(t & 15) * 65536 + (size_t)(m0 + erow) * 512 + cs * 32 + ecp;
        st32_sys(h1ring + eo, pk);
      }
      __syncthreads();                                   // S5: loop end
    }
  }
  vm_drain();   // flush final h stores before exit (last consumers still polling)
}

// ---------------- projection role ----------------
__device__ void proj_role(char* smem, int bg, int tid,
    const u16* __restrict__ h1ring, u32* __restrict__ FP,
    const short* __restrict__ pWswz, const float* __restrict__ lng,
    const float* __restrict__ lnb, const float* __restrict__ pb,
    float* __restrict__ out)
{
  const int w = tid >> 6, lane = tid & 63, l15 = lane & 15, lq = lane >> 4;
  const int m0 = bg * 16;
  const short* bp0 = pWswz + (size_t)(w * 2) * 8192 + lane * 8;
  const short* bp1 = bp0 + 8192;
  const int swzrow = (l15 & 7) << 4;
  float pb0 = pb[(w * 2) * 16 + l15], pb1 = pb[(w * 2 + 1) * 16 + l15];
  const int sg = tid & 63;

  for (int t = 0; t < 1024; ++t) {
    {
      const u32 pm = ((t >> 4) & 1) ? 0x00010001u : 0u;   // h1 epoch t
      const u16* src = h1ring + (size_t)(t & 15) * 65536 + (size_t)m0 * 512;
      const int r0 = tid >> 6, r1 = r0 + 8;
      u32x4 v[2];
      v[0] = ld128_sys(src + r0 * 512 + sg * 8);
      v[1] = ld128_sys(src + r1 * 512 + sg * 8);
      int pend = 3;
      while (pend) {
        vm_drain();
        int np = 0;
        if (pend & 1) {
          if (par_ok(v[0], pm))
            *reinterpret_cast<u32x4*>(smem + r0 * 1024 + sg * 16) = v[0];
          else { np |= 1; v[0] = ld128_sys(src + r0 * 512 + sg * 8); }
        }
        if (pend & 2) {
          if (par_ok(v[1], pm))
            *reinterpret_cast<u32x4*>(smem + r1 * 1024 + sg * 16) = v[1];
          else { np |= 2; v[1] = ld128_sys(src + r1 * 512 + sg * 8); }
        }
        pend = np;
      }
    }
    __syncthreads();
    if (tid == 0) st_flag(&FP[(192 + bg) * 4], (u32)(t + 1));
    {
      int row = tid >> 5, j = tid & 31;
      const u16* hr = reinterpret_cast<const u16*>(smem) + row * 512;
      float s1 = 0.f, s2 = 0.f;
#pragma unroll
      for (int kk = 0; kk < 16; ++kk) {
        float v = bf2f(hr[j + kk * 32]);
        s1 += v; s2 += v * v;
      }
#pragma unroll
      for (int d = 1; d < 32; d <<= 1) { s1 += __shfl_xor(s1, d, 32); s2 += __shfl_xor(s2, d, 32); }
      float mu = s1 * (1.f / 512.f);
      float rs = rsqrtf(s2 * (1.f / 512.f) - mu * mu + 1e-5f);
      char* zn = smem + 16384;
#pragma unroll
      for (int kk = 0; kk < 16; ++kk) {
        int kcol = j + kk * 32;
        float v = bf2f(hr[kcol]);
        float nv = (v - mu) * rs * lng[kcol] + lnb[kcol];
        *reinterpret_cast<short*>(zn + row * 1024 + ((kcol * 2) ^ ((row & 7) << 4))) = f2bf(nv);
      }
    }
    __syncthreads();
    const char* ap = smem + 16384 + (size_t)l15 * 1024;
    f32x4 acc[2][2] = {};
#pragma unroll 4
    for (int ks = 0; ks < 16; ++ks) {
      bf16x8 a = *reinterpret_cast<const bf16x8*>(ap + ((ks * 64 + lq * 16) ^ swzrow));
      bf16x8 b0 = *reinterpret_cast<const bf16x8*>(bp0 + ks * 512);
      bf16x8 b1 = *reinterpret_cast<const bf16x8*>(bp1 + ks * 512);
      acc[0][ks & 1] = __builtin_amdgcn_mfma_f32_16x16x32_bf16(a, b0, acc[0][ks & 1], 0, 0, 0);
      acc[1][ks & 1] = __builtin_amdgcn_mfma_f32_16x16x32_bf16(a, b1, acc[1][ks & 1], 0, 0, 0);
    }
#pragma unroll
    for (int nfi = 0; nfi < 2; ++nfi) {
      int vcol = (w * 2 + nfi) * 16 + l15;
      float pbv = nfi ? pb1 : pb0;
#pragma unroll
      for (int r = 0; r < 4; ++r) {
        float vv = acc[nfi][0][r] + acc[nfi][1][r] + pbv;
        out[(size_t)(m0 + lq * 4 + r) * 262144 + (size_t)t * 256 + vcol] = vv;
      }
    }
    __syncthreads();
  }
}

// Grid: 200 blocks. 0..127 = L1, 128..191 = L0, 192..199 = proj.
__global__ __launch_bounds__(512, 1) void persist_kernel(
    const short* __restrict__ W0h, const short* __restrict__ W1,
    const float* __restrict__ table, const float* __restrict__ bias1,
    const int* __restrict__ xT,
    u16* __restrict__ h0ring, u16* __restrict__ h1ring, u32* __restrict__ flags,
    const short* __restrict__ pWswz, const float* __restrict__ lng,
    const float* __restrict__ lnb, const float* __restrict__ pb, float* __restrict__ out)
{
  __shared__ __align__(16) char smem[49408];
  const int bid = blockIdx.x, tid = threadIdx.x;
  if (bid < 128) {
    lstm_role<1>(smem, bid >> 4, bid & 15, tid, W1, nullptr, bias1, xT,
                 h0ring, h1ring, flags);
  } else if (bid < 192) {
    int idx = bid - 128;
    lstm_role<0>(smem, idx >> 3, idx & 7, tid, W0h, table, nullptr, xT,
                 h0ring, h1ring, flags);
  } else {
    proj_role(smem, bid - 192, tid, h1ring, flags, pWswz, lng, lnb, pb, out);
  }
}

extern "C" void kernel_launch(void* const* d_in, const int* in_sizes, int n_in,
                              void* d_out, int out_size, void* d_ws, size_t ws_size,
                              hipStream_t stream) {
  const int*   x    = (const int*)d_in[0];
  const float* emb  = (const float*)d_in[1];
  const float* W    = (const float*)d_in[2];
  const float* bias = (const float*)d_in[3];
  const float* lng  = (const float*)d_in[4];
  const float* lnb  = (const float*)d_in[5];
  const float* pW   = (const float*)d_in[6];
  const float* pb   = (const float*)d_in[7];
  float* out = (float*)d_out;

  char* ws = (char*)d_ws;
  short* W0h   = (short*)(ws + 0);           // 2 MB
  short* W1sw  = (short*)(ws + 2097152);     // 4 MB
  short* pWsw  = (short*)(ws + 6291456);     // 256 KB
  float* table = (float*)(ws + 6815744);     // 2 MB
  int*   xT    = (int*)(ws + 8912896);       // 512 KB
  u32*   flags = (u32*)(ws + 9437184);       // 4 KB (prog)
  u16*   h0ring= (u16*)(ws + 9961472);       // 2 MB: 16 x [128][512] bf16 (parity LSB)
  u16*   h1ring= (u16*)(ws + 12058624);      // 2 MB
  short* W0x   = (short*)(ws + 14155776);    // 2 MB temp (table build)

  swz_generic<<<dim3(512), dim3(256), 0, stream>>>(W, W0h, 1024, 512, 16, 131072);
  swz_generic<<<dim3(1024), dim3(256), 0, stream>>>(W + 2048 * 1024, W1sw, 1024, 0, 32, 262144);
  swz_generic<<<dim3(64), dim3(256), 0, stream>>>(pW, pWsw, 512, 0, 16, 16384);
  xpose_kernel<<<dim3(512), dim3(256), 0, stream>>>(x, xT);
  swz_generic<<<dim3(512), dim3(256), 0, stream>>>(W, W0x, 1024, 0, 16, 131072);
  table_kernel<<<dim3(4, 16), dim3(512), 0, stream>>>(emb, W0x, bias, table);
  hipMemsetAsync(ws + 9437184, 0, 4096, stream);          // prog flags
  hipMemsetAsync(ws + 9961472, 0x01, 4194304, stream);    // rings: LSB=1 rejects first-epoch reads

  persist_kernel<<<dim3(200), dim3(512), 0, stream>>>(
      W0h, W1sw, table, bias + 2048, xT, h0ring, h1ring, flags,
      pWsw, lng, lnb, pb, out);
}

// Round 13
// 3933.207 us; speedup vs baseline: 2.7605x; 1.2738x over previous
//
#include <hip/hip_runtime.h>
#include <hip/hip_bf16.h>

typedef __attribute__((ext_vector_type(8))) short bf16x8;
typedef __attribute__((ext_vector_type(4))) float f32x4;
typedef __attribute__((ext_vector_type(4))) unsigned int u32x4;
typedef unsigned int u32;
typedef unsigned long long u64;
typedef unsigned short u16;

__device__ __forceinline__ short f2bf(float f) {
  __hip_bfloat16 h = __float2bfloat16(f);
  return *reinterpret_cast<short*>(&h);
}
__device__ __forceinline__ float bf2f(u16 s) {
  __hip_bfloat16 h;
  *reinterpret_cast<u16*>(&h) = s;
  return __bfloat162float(h);
}
__device__ __forceinline__ float sigm(float x) { return 1.f / (1.f + __expf(-x)); }

// ---- MALL-coherent transport (R7-proven) ----
__device__ __forceinline__ u32x4 ld128_sys(const void* p) {
  u32x4 r;
  asm volatile("global_load_dwordx4 %0, %1, off sc0 sc1"
               : "=v"(r) : "v"((u64)(uintptr_t)p) : "memory");
  return r;
}
__device__ __forceinline__ void st32_sys(void* p, u32 v) {
  asm volatile("global_store_dword %0, %1, off sc0 sc1"
               :: "v"((u64)(uintptr_t)p), "v"(v) : "memory");
}
__device__ __forceinline__ void vm_drain() {
  asm volatile("s_waitcnt vmcnt(0)" ::: "memory");
  __builtin_amdgcn_sched_barrier(0);
}
__device__ __forceinline__ void vm_wait2() {
  asm volatile("s_waitcnt vmcnt(2)" ::: "memory");
  __builtin_amdgcn_sched_barrier(0);
}
__device__ __forceinline__ u32 ld_flag(const u32* p) {
  return __hip_atomic_load(const_cast<u32*>(p), __ATOMIC_RELAXED, __HIP_MEMORY_SCOPE_AGENT);
}
__device__ __forceinline__ void st_flag(u32* p, u32 v) {
  __hip_atomic_store(p, v, __ATOMIC_RELAXED, __HIP_MEMORY_SCOPE_AGENT);
}
// parity check: all 8 bf16 LSBs in a 16B granule == p?  (pm = p ? 0x00010001 : 0)
__device__ __forceinline__ bool par_ok(u32x4 v, u32 pm) {
  u32 z = ((v[0] ^ pm) | (v[1] ^ pm) | (v[2] ^ pm) | (v[3] ^ pm)) & 0x00010001u;
  return z == 0;
}

// ---------------- precompute kernels ----------------
__global__ void swz_generic(const float* __restrict__ src, short* __restrict__ dst,
                            int row_stride, int col_off, int nks, int nunits) {
  int uid = blockIdx.x * blockDim.x + threadIdx.x;
  if (uid >= nunits) return;
  int lane = uid & 63;
  int rem  = uid >> 6;
  int ks = rem % nks;
  int nf = rem / nks;
  int row = nf * 16 + (lane & 15);
  int k0  = col_off + ks * 32 + (lane >> 4) * 8;
  const float* s = src + (size_t)row * row_stride + k0;
  short v[8];
#pragma unroll
  for (int e = 0; e < 8; ++e) v[e] = f2bf(s[e]);
  *reinterpret_cast<int4*>(dst + (size_t)uid * 8) = *reinterpret_cast<int4*>(v);
}

__global__ void xpose_kernel(const int* __restrict__ x, int* __restrict__ xT) {
  int i = blockIdx.x * blockDim.x + threadIdx.x;   // 131072
  int b = i >> 10, t = i & 1023;
  xT[t * 128 + b] = x[i];
}

__global__ __launch_bounds__(512) void table_kernel(
    const float* __restrict__ emb, const short* __restrict__ Wx,
    const float* __restrict__ b0, float* __restrict__ table) {
  __shared__ __align__(16) char smem[65536];
  const int tid = threadIdx.x;
  const int m0 = blockIdx.x * 64;
  const int nt = blockIdx.y;
  for (int i = tid; i < 4096; i += 512) {
    int row = i >> 6, seg = i & 63;
    const float* sp = emb + (size_t)(m0 + row) * 512 + seg * 8;
    short v[8];
#pragma unroll
    for (int e = 0; e < 8; ++e) v[e] = f2bf(sp[e]);
    *reinterpret_cast<int4*>(smem + row * 1024 + ((seg * 16) ^ ((row & 7) << 4))) =
        *reinterpret_cast<int4*>(v);
  }
  __syncthreads();
  const int w = tid >> 6, lane = tid & 63, l15 = lane & 15, lq = lane >> 4;
  const int mg = (w >> 2) * 32, np = w & 3;
  const char* ap = smem + (mg + l15) * 1024;
  const int swz = (l15 & 7) << 4;
  const int nfbase = nt * 8 + np * 2;
  const short* bp0 = Wx + (size_t)nfbase * 8192 + lane * 8;
  const short* bp1 = bp0 + 8192;
  f32x4 acc[2][2] = {};
#pragma unroll 4
  for (int ks = 0; ks < 16; ++ks) {
    int kb = ks * 64 + lq * 16;
    bf16x8 a0 = *reinterpret_cast<const bf16x8*>(ap + (kb ^ swz));
    bf16x8 a1 = *reinterpret_cast<const bf16x8*>(ap + 16 * 1024 + (kb ^ swz));
    bf16x8 bv0 = *reinterpret_cast<const bf16x8*>(bp0 + ks * 512);
    bf16x8 bv1 = *reinterpret_cast<const bf16x8*>(bp1 + ks * 512);
    acc[0][0] = __builtin_amdgcn_mfma_f32_16x16x32_bf16(a0, bv0, acc[0][0], 0, 0, 0);
    acc[1][0] = __builtin_amdgcn_mfma_f32_16x16x32_bf16(a1, bv0, acc[1][0], 0, 0, 0);
    acc[0][1] = __builtin_amdgcn_mfma_f32_16x16x32_bf16(a0, bv1, acc[0][1], 0, 0, 0);
    acc[1][1] = __builtin_amdgcn_mfma_f32_16x16x32_bf16(a1, bv1, acc[1][1], 0, 0, 0);
  }
#pragma unroll
  for (int mf = 0; mf < 2; ++mf)
#pragma unroll
    for (int nfi = 0; nfi < 2; ++nfi)
#pragma unroll
      for (int r = 0; r < 4; ++r) {
        int ncol = nt * 128 + np * 32 + nfi * 16 + l15;
        int vrow = m0 + mg + mf * 16 + lq * 4 + r;
        table[(size_t)vrow * 2048 + ncol] = acc[mf][nfi][r] + b0[ncol];
      }
}

// ---------------- LSTM role (M_wg = 16 rows) ----------------
// B-panel partially cached in LDS (one-time preload; weights immutable):
//   L0: bb0 ks 0..7 + bb1 ks 0..6 (120 KB). L1: bb0 ks 0..13 (112 KB).
template<int L>
__device__ void lstm_role(char* smem, int bg, int cs, int tid,
    const short* __restrict__ Wsw, const float* __restrict__ table,
    const float* __restrict__ bias1, const int* __restrict__ xT,
    u16* __restrict__ h0ring, u16* __restrict__ h1ring, u32* __restrict__ FP)
{
  constexpr int NCOL = (L == 0) ? 64 : 32;
  constexpr int NKS  = (L == 0) ? 16 : 32;
  constexpr int ROWB = (L == 0) ? 1024 : 2048;
  const int w = tid >> 6, lane = tid & 63, l15 = lane & 15, lq = lane >> 4;
  const int g = w >> 1;
  const int m0 = bg * 16;
  const int myid = (L == 0) ? (128 + bg * 8 + cs) : (bg * 16 + cs);
  const int nf0 = g * 32 + cs * (NCOL / 16) + (w & 1) * ((L == 0) ? 2 : 1);
  const short* bb0 = Wsw + (size_t)nf0 * (NKS * 512) + lane * 8;
  const short* bb1 = (L == 0) ? bb0 + (size_t)(NKS * 512) : nullptr;
  float* glf = reinterpret_cast<float*>(smem + ((L == 0) ? 16384 : 32768));
  const int swz = (l15 & 7) << 4;
  const bool ew = (L == 0) ? true : (tid < 256);
  const int erow = (L == 0) ? (tid >> 5) : (tid >> 4);
  const int ecp  = (L == 0) ? ((tid & 31) * 2) : ((tid & 15) * 2);
  const int esh  = ((erow >> 2) & 3) * 8;          // gate-exchange rotation
  float c0 = 0.f, c1 = 0.f;
  float2 breg[4];
  if (L == 1 && ew) {
#pragma unroll
    for (int gg = 0; gg < 4; ++gg)
      breg[gg] = *reinterpret_cast<const float2*>(bias1 + gg * 512 + cs * 32 + ecp);
  }
  const int sg = tid & 63;

  // ---- one-time B-panel preload into LDS ----
  char* bcache;
  if (L == 0) {
    bcache = smem + 32768 + w * 15360;           // 8 KB bb0 + 7 KB bb1 per wave
#pragma unroll
    for (int ks = 0; ks < 8; ++ks)
      *reinterpret_cast<u32x4*>(bcache + ks * 1024 + lane * 16) =
          *reinterpret_cast<const u32x4*>(bb0 + ks * 512);
#pragma unroll
    for (int ks = 0; ks < 7; ++ks)
      *reinterpret_cast<u32x4*>(bcache + 8192 + ks * 1024 + lane * 16) =
          *reinterpret_cast<const u32x4*>(bb1 + ks * 512);
  } else {
    bcache = smem + 40960 + w * 14336;           // 14 KB bb0 per wave
#pragma unroll
    for (int ks = 0; ks < 14; ++ks)
      *reinterpret_cast<u32x4*>(bcache + ks * 1024 + lane * 16) =
          *reinterpret_cast<const u32x4*>(bb0 + ks * 512);
  }
  __syncthreads();

  for (int t = 0; t < 1024; ++t) {
    // ---- backpressure (every 8 ticks, FP only) ----
    if (((t & 7) == 0) && t >= 16) {
      if (w == 0) {
        const u32* a = nullptr;
        if (L == 0) {
          if (lane < 16)      a = &FP[(bg * 16 + lane) * 4];          // L1 consumers of h0
          else if (lane < 24) a = &FP[(128 + bg * 8 + lane - 16) * 4];// L0 peers
        } else {
          if (lane < 16)      a = &FP[(bg * 16 + lane) * 4];          // L1 peers
          else if (lane == 16) a = &FP[(192 + bg) * 4];               // proj
        }
        if (a) { u32 tgt = (u32)(t - 6); while (ld_flag(a) < tgt) __builtin_amdgcn_s_sleep(1); }
      }
    }

    if (L == 0) {
      // ---- stage h0(t-1): parity-validated retry -> bf16 XOR-swizzled LDS ----
      const u32 pm = (((t - 1) >> 4) & 1) ? 0x00010001u : 0u;
      const u16* s0 = h0ring + (size_t)((t + 15) & 15) * 65536 + (size_t)m0 * 512;
      u32x4 v[2];
      const int r0 = tid >> 6, r1 = r0 + 8;
      if (t > 0) {
        v[0] = ld128_sys(s0 + r0 * 512 + sg * 8);
        v[1] = ld128_sys(s0 + r1 * 512 + sg * 8);
        int pend = 3;
        while (pend) {
          vm_drain();
          int np = 0;
          if (pend & 1) {
            if (par_ok(v[0], pm))
              *reinterpret_cast<u32x4*>(smem + r0 * 1024 + ((sg * 16) ^ ((r0 & 7) << 4))) = v[0];
            else { np |= 1; v[0] = ld128_sys(s0 + r0 * 512 + sg * 8); }
          }
          if (pend & 2) {
            if (par_ok(v[1], pm))
              *reinterpret_cast<u32x4*>(smem + r1 * 1024 + ((sg * 16) ^ ((r1 & 7) << 4))) = v[1];
            else { np |= 2; v[1] = ld128_sys(s0 + r1 * 512 + sg * 8); }
          }
          pend = np;
        }
      } else {
        u32x4 z = {0, 0, 0, 0};
        *reinterpret_cast<u32x4*>(smem + r0 * 1024 + ((sg * 16) ^ ((r0 & 7) << 4))) = z;
        *reinterpret_cast<u32x4*>(smem + r1 * 1024 + ((sg * 16) ^ ((r1 & 7) << 4))) = z;
      }
      __syncthreads();                                   // S2: staging ready
      if (tid == 0) st_flag(&FP[myid * 4], (u32)(t + 1));
      // per-thread vocab id + table prefetch (overlaps MFMA)
      int vid = xT[t * 128 + m0 + erow];
      const float* tp = table + (size_t)vid * 2048 + cs * 64 + ecp;
      float2 tbi = *reinterpret_cast<const float2*>(tp);
      float2 tbf = *reinterpret_cast<const float2*>(tp + 512);
      float2 tbo = *reinterpret_cast<const float2*>(tp + 1024);
      float2 tbg = *reinterpret_cast<const float2*>(tp + 1536);
      // ---- MFMA (B from LDS for ks<8 / ks<7, else L2) ----
      const char* ap = smem + (size_t)l15 * ROWB;
      f32x4 acc[2][2] = {};
#pragma unroll
      for (int ks = 0; ks < 16; ++ks) {
        bf16x8 a = *reinterpret_cast<const bf16x8*>(ap + ((ks * 64 + lq * 16) ^ swz));
        bf16x8 b0 = (ks < 8)
          ? *reinterpret_cast<const bf16x8*>(bcache + ks * 1024 + lane * 16)
          : *reinterpret_cast<const bf16x8*>(bb0 + ks * 512);
        bf16x8 b1 = (ks < 7)
          ? *reinterpret_cast<const bf16x8*>(bcache + 8192 + ks * 1024 + lane * 16)
          : *reinterpret_cast<const bf16x8*>(bb1 + ks * 512);
        acc[0][ks & 1] = __builtin_amdgcn_mfma_f32_16x16x32_bf16(a, b0, acc[0][ks & 1], 0, 0, 0);
        acc[1][ks & 1] = __builtin_amdgcn_mfma_f32_16x16x32_bf16(a, b1, acc[1][ks & 1], 0, 0, 0);
      }
      // (no barrier: glf [16K,32K) does not alias staging [0,16K))
#pragma unroll
      for (int nfi = 0; nfi < 2; ++nfi) {
        int col = ((w & 1) * 2 + nfi) * 16 + l15;
#pragma unroll
        for (int r = 0; r < 4; ++r) {
          int lrow = lq * 4 + r;
          glf[(g * 16 + lrow) * 64 + ((col + (lrow >> 2) * 8) & 63)] =
              acc[nfi][0][r] + acc[nfi][1][r];
        }
      }
      __syncthreads();                                   // S4: exchange ready
      // ---- elementwise ----
      int cidx = (ecp + esh) & 63;
      float2 vi = *reinterpret_cast<float2*>(&glf[(0 * 16 + erow) * 64 + cidx]);
      float2 vf = *reinterpret_cast<float2*>(&glf[(1 * 16 + erow) * 64 + cidx]);
      float2 vo = *reinterpret_cast<float2*>(&glf[(2 * 16 + erow) * 64 + cidx]);
      float2 vg = *reinterpret_cast<float2*>(&glf[(3 * 16 + erow) * 64 + cidx]);
      float cv0 = sigm(vf.x + tbf.x) * c0 + sigm(vi.x + tbi.x) * tanhf(vg.x + tbg.x);
      float cv1 = sigm(vf.y + tbf.y) * c1 + sigm(vi.y + tbi.y) * tanhf(vg.y + tbg.y);
      c0 = cv0; c1 = cv1;
      float h0v = sigm(vo.x + tbo.x) * tanhf(cv0);
      float h1v = sigm(vo.y + tbo.y) * tanhf(cv1);
      u32 po = (u32)((t >> 4) & 1);
      u32 pk = (((u32)(u16)f2bf(h0v) & ~1u) | po)
             | ((((u32)(u16)f2bf(h1v) & ~1u) | po) << 16);
      size_t eo = (size_t)(t & 15) * 65536 + (size_t)(m0 + erow) * 512 + cs * 64 + ecp;
      st32_sys(h0ring + eo, pk);
      __syncthreads();                                   // S5: loop end
    } else {
      // ---- L1: issue h0 then h1; validate h0 first; compute h0-half MFMAs
      //      while h1 stores gain visibility time ----
      const u32 pm0 = ((t >> 4) & 1) ? 0x00010001u : 0u;         // h0 epoch t
      const u32 pm1 = (((t - 1) >> 4) & 1) ? 0x00010001u : 0u;   // h1 epoch t-1
      const u16* s0 = h0ring + (size_t)(t & 15) * 65536 + (size_t)m0 * 512;
      const u16* s1 = h1ring + (size_t)((t + 15) & 15) * 65536 + (size_t)m0 * 512;
      const int r0 = tid >> 6, r1 = r0 + 8;
      u32x4 v[4];
      v[0] = ld128_sys(s0 + r0 * 512 + sg * 8);
      v[1] = ld128_sys(s0 + r1 * 512 + sg * 8);
      if (t > 0) {
        v[2] = ld128_sys(s1 + r0 * 512 + sg * 8);
        v[3] = ld128_sys(s1 + r1 * 512 + sg * 8);
      } else {
        u32x4 z = {0, 0, 0, 0};
        *reinterpret_cast<u32x4*>(smem + r0 * 2048 + ((1024 + sg * 16) ^ ((r0 & 7) << 4))) = z;
        *reinterpret_cast<u32x4*>(smem + r1 * 2048 + ((1024 + sg * 16) ^ ((r1 & 7) << 4))) = z;
      }
      if (t > 0) vm_wait2(); else vm_drain();
      {
        int pend = 0;
        if (par_ok(v[0], pm0))
          *reinterpret_cast<u32x4*>(smem + r0 * 2048 + ((sg * 16) ^ ((r0 & 7) << 4))) = v[0];
        else pend |= 1;
        if (par_ok(v[1], pm0))
          *reinterpret_cast<u32x4*>(smem + r1 * 2048 + ((sg * 16) ^ ((r1 & 7) << 4))) = v[1];
        else pend |= 2;
        while (pend) {
          if (pend & 1) v[0] = ld128_sys(s0 + r0 * 512 + sg * 8);
          if (pend & 2) v[1] = ld128_sys(s0 + r1 * 512 + sg * 8);
          vm_drain();
          int np = 0;
          if (pend & 1) {
            if (par_ok(v[0], pm0))
              *reinterpret_cast<u32x4*>(smem + r0 * 2048 + ((sg * 16) ^ ((r0 & 7) << 4))) = v[0];
            else np |= 1;
          }
          if (pend & 2) {
            if (par_ok(v[1], pm0))
              *reinterpret_cast<u32x4*>(smem + r1 * 2048 + ((sg * 16) ^ ((r1 & 7) << 4))) = v[1];
            else np |= 2;
          }
          pend = np;
        }
      }
      __syncthreads();                                   // S2a: h0 staged
      // ---- MFMA h0-half (ks 0..15): B from LDS for ks<14 ----
      const char* ap = smem + (size_t)l15 * ROWB;
      f32x4 acca = {}, accb = {};
#pragma unroll
      for (int ks = 0; ks < 16; ++ks) {
        bf16x8 a = *reinterpret_cast<const bf16x8*>(ap + ((ks * 64 + lq * 16) ^ swz));
        bf16x8 b0 = (ks < 14)
          ? *reinterpret_cast<const bf16x8*>(bcache + ks * 1024 + lane * 16)
          : *reinterpret_cast<const bf16x8*>(bb0 + ks * 512);
        if (ks & 1) accb = __builtin_amdgcn_mfma_f32_16x16x32_bf16(a, b0, accb, 0, 0, 0);
        else        acca = __builtin_amdgcn_mfma_f32_16x16x32_bf16(a, b0, acca, 0, 0, 0);
      }
      // ---- validate h1 (t-1) ----
      if (t > 0) {
        int pend = 0xC;
        while (pend) {
          vm_drain();
          int np = 0;
          if (pend & 4) {
            if (par_ok(v[2], pm1))
              *reinterpret_cast<u32x4*>(smem + r0 * 2048 + ((1024 + sg * 16) ^ ((r0 & 7) << 4))) = v[2];
            else { np |= 4; v[2] = ld128_sys(s1 + r0 * 512 + sg * 8); }
          }
          if (pend & 8) {
            if (par_ok(v[3], pm1))
              *reinterpret_cast<u32x4*>(smem + r1 * 2048 + ((1024 + sg * 16) ^ ((r1 & 7) << 4))) = v[3];
            else { np |= 8; v[3] = ld128_sys(s1 + r1 * 512 + sg * 8); }
          }
          pend = np;
        }
      }
      __syncthreads();                                   // S2b: h1 staged
      if (tid == 0) st_flag(&FP[myid * 4], (u32)(t + 1));
      // ---- MFMA h1-half (ks 16..31, B from L2) ----
#pragma unroll 4
      for (int ks = 16; ks < 32; ++ks) {
        bf16x8 a = *reinterpret_cast<const bf16x8*>(ap + ((ks * 64 + lq * 16) ^ swz));
        bf16x8 b0 = *reinterpret_cast<const bf16x8*>(bb0 + ks * 512);
        if (ks & 1) accb = __builtin_amdgcn_mfma_f32_16x16x32_bf16(a, b0, accb, 0, 0, 0);
        else        acca = __builtin_amdgcn_mfma_f32_16x16x32_bf16(a, b0, acca, 0, 0, 0);
      }
      // (no barrier: glf [32K,41K) does not alias staging [0,32K))
      {
        int col = (w & 1) * 16 + l15;
#pragma unroll
        for (int r = 0; r < 4; ++r) {
          int lrow = lq * 4 + r;
          glf[(g * 16 + lrow) * 32 + ((col + (lrow >> 2) * 8) & 31)] = acca[r] + accb[r];
        }
      }
      __syncthreads();                                   // S4: exchange ready
      if (ew) {
        int cidx = (ecp + esh) & 31;
        float2 vi = *reinterpret_cast<float2*>(&glf[(0 * 16 + erow) * 32 + cidx]);
        float2 vf = *reinterpret_cast<float2*>(&glf[(1 * 16 + erow) * 32 + cidx]);
        float2 vo = *reinterpret_cast<float2*>(&glf[(2 * 16 + erow) * 32 + cidx]);
        float2 vg = *reinterpret_cast<float2*>(&glf[(3 * 16 + erow) * 32 + cidx]);
        float cv0 = sigm(vf.x + breg[1].x) * c0 + sigm(vi.x + breg[0].x) * tanhf(vg.x + breg[3].x);
        float cv1 = sigm(vf.y + breg[1].y) * c1 + sigm(vi.y + breg[0].y) * tanhf(vg.y + breg[3].y);
        c0 = cv0; c1 = cv1;
        float h0v = sigm(vo.x + breg[2].x) * tanhf(cv0);
        float h1v = sigm(vo.y + breg[2].y) * tanhf(cv1);
        u32 po = (u32)((t >> 4) & 1);
        u32 pk = (((u32)(u16)f2bf(h0v) & ~1u) | po)
               | ((((u32)(u16)f2bf(h1v) & ~1u) | po) << 16);
        size_t eo = (size_t)(t & 15) * 65536 + (size_t)(m0 + erow) * 512 + cs * 32 + ecp;
        st32_sys(h1ring + eo, pk);
      }
      __syncthreads();                                   // S5: loop end
    }
  }
  vm_drain();   // flush final h stores before exit (last consumers still polling)
}

// ---------------- projection role ----------------
__device__ void proj_role(char* smem, int bg, int tid,
    const u16* __restrict__ h1ring, u32* __restrict__ FP,
    const short* __restrict__ pWswz, const float* __restrict__ lng,
    const float* __restrict__ lnb, const float* __restrict__ pb,
    float* __restrict__ out)
{
  const int w = tid >> 6, lane = tid & 63, l15 = lane & 15, lq = lane >> 4;
  const int m0 = bg * 16;
  const short* bp0 = pWswz + (size_t)(w * 2) * 8192 + lane * 8;
  const short* bp1 = bp0 + 8192;
  const int swzrow = (l15 & 7) << 4;
  float pb0 = pb[(w * 2) * 16 + l15], pb1 = pb[(w * 2 + 1) * 16 + l15];
  const int sg = tid & 63;

  for (int t = 0; t < 1024; ++t) {
    {
      const u32 pm = ((t >> 4) & 1) ? 0x00010001u : 0u;   // h1 epoch t
      const u16* src = h1ring + (size_t)(t & 15) * 65536 + (size_t)m0 * 512;
      const int r0 = tid >> 6, r1 = r0 + 8;
      u32x4 v[2];
      v[0] = ld128_sys(src + r0 * 512 + sg * 8);
      v[1] = ld128_sys(src + r1 * 512 + sg * 8);
      int pend = 3;
      while (pend) {
        vm_drain();
        int np = 0;
        if (pend & 1) {
          if (par_ok(v[0], pm))
            *reinterpret_cast<u32x4*>(smem + r0 * 1024 + sg * 16) = v[0];
          else { np |= 1; v[0] = ld128_sys(src + r0 * 512 + sg * 8); }
        }
        if (pend & 2) {
          if (par_ok(v[1], pm))
            *reinterpret_cast<u32x4*>(smem + r1 * 1024 + sg * 16) = v[1];
          else { np |= 2; v[1] = ld128_sys(src + r1 * 512 + sg * 8); }
        }
        pend = np;
      }
    }
    __syncthreads();
    if (tid == 0) st_flag(&FP[(192 + bg) * 4], (u32)(t + 1));
    {
      int row = tid >> 5, j = tid & 31;
      const u16* hr = reinterpret_cast<const u16*>(smem) + row * 512;
      float s1 = 0.f, s2 = 0.f;
#pragma unroll
      for (int kk = 0; kk < 16; ++kk) {
        float v = bf2f(hr[j + kk * 32]);
        s1 += v; s2 += v * v;
      }
#pragma unroll
      for (int d = 1; d < 32; d <<= 1) { s1 += __shfl_xor(s1, d, 32); s2 += __shfl_xor(s2, d, 32); }
      float mu = s1 * (1.f / 512.f);
      float rs = rsqrtf(s2 * (1.f / 512.f) - mu * mu + 1e-5f);
      char* zn = smem + 16384;
#pragma unroll
      for (int kk = 0; kk < 16; ++kk) {
        int kcol = j + kk * 32;
        float v = bf2f(hr[kcol]);
        float nv = (v - mu) * rs * lng[kcol] + lnb[kcol];
        *reinterpret_cast<short*>(zn + row * 1024 + ((kcol * 2) ^ ((row & 7) << 4))) = f2bf(nv);
      }
    }
    __syncthreads();
    const char* ap = smem + 16384 + (size_t)l15 * 1024;
    f32x4 acc[2][2] = {};
#pragma unroll 4
    for (int ks = 0; ks < 16; ++ks) {
      bf16x8 a = *reinterpret_cast<const bf16x8*>(ap + ((ks * 64 + lq * 16) ^ swzrow));
      bf16x8 b0 = *reinterpret_cast<const bf16x8*>(bp0 + ks * 512);
      bf16x8 b1 = *reinterpret_cast<const bf16x8*>(bp1 + ks * 512);
      acc[0][ks & 1] = __builtin_amdgcn_mfma_f32_16x16x32_bf16(a, b0, acc[0][ks & 1], 0, 0, 0);
      acc[1][ks & 1] = __builtin_amdgcn_mfma_f32_16x16x32_bf16(a, b1, acc[1][ks & 1], 0, 0, 0);
    }
#pragma unroll
    for (int nfi = 0; nfi < 2; ++nfi) {
      int vcol = (w * 2 + nfi) * 16 + l15;
      float pbv = nfi ? pb1 : pb0;
#pragma unroll
      for (int r = 0; r < 4; ++r) {
        float vv = acc[nfi][0][r] + acc[nfi][1][r] + pbv;
        out[(size_t)(m0 + lq * 4 + r) * 262144 + (size_t)t * 256 + vcol] = vv;
      }
    }
    __syncthreads();
  }
}

// Grid: 200 blocks. 0..127 = L1, 128..191 = L0, 192..199 = proj.
__global__ __launch_bounds__(512, 1) void persist_kernel(
    const short* __restrict__ W0h, const short* __restrict__ W1,
    const float* __restrict__ table, const float* __restrict__ bias1,
    const int* __restrict__ xT,
    u16* __restrict__ h0ring, u16* __restrict__ h1ring, u32* __restrict__ flags,
    const short* __restrict__ pWswz, const float* __restrict__ lng,
    const float* __restrict__ lnb, const float* __restrict__ pb, float* __restrict__ out)
{
  __shared__ __align__(16) char smem[155648];
  const int bid = blockIdx.x, tid = threadIdx.x;
  if (bid < 128) {
    lstm_role<1>(smem, bid >> 4, bid & 15, tid, W1, nullptr, bias1, xT,
                 h0ring, h1ring, flags);
  } else if (bid < 192) {
    int idx = bid - 128;
    lstm_role<0>(smem, idx >> 3, idx & 7, tid, W0h, table, nullptr, xT,
                 h0ring, h1ring, flags);
  } else {
    proj_role(smem, bid - 192, tid, h1ring, flags, pWswz, lng, lnb, pb, out);
  }
}

extern "C" void kernel_launch(void* const* d_in, const int* in_sizes, int n_in,
                              void* d_out, int out_size, void* d_ws, size_t ws_size,
                              hipStream_t stream) {
  const int*   x    = (const int*)d_in[0];
  const float* emb  = (const float*)d_in[1];
  const float* W    = (const float*)d_in[2];
  const float* bias = (const float*)d_in[3];
  const float* lng  = (const float*)d_in[4];
  const float* lnb  = (const float*)d_in[5];
  const float* pW   = (const float*)d_in[6];
  const float* pb   = (const float*)d_in[7];
  float* out = (float*)d_out;

  char* ws = (char*)d_ws;
  short* W0h   = (short*)(ws + 0);           // 2 MB
  short* W1sw  = (short*)(ws + 2097152);     // 4 MB
  short* pWsw  = (short*)(ws + 6291456);     // 256 KB
  float* table = (float*)(ws + 6815744);     // 2 MB
  int*   xT    = (int*)(ws + 8912896);       // 512 KB
  u32*   flags = (u32*)(ws + 9437184);       // 4 KB (prog)
  u16*   h0ring= (u16*)(ws + 9961472);       // 2 MB: 16 x [128][512] bf16 (parity LSB)
  u16*   h1ring= (u16*)(ws + 12058624);      // 2 MB
  short* W0x   = (short*)(ws + 14155776);    // 2 MB temp (table build)

  swz_generic<<<dim3(512), dim3(256), 0, stream>>>(W, W0h, 1024, 512, 16, 131072);
  swz_generic<<<dim3(1024), dim3(256), 0, stream>>>(W + 2048 * 1024, W1sw, 1024, 0, 32, 262144);
  swz_generic<<<dim3(64), dim3(256), 0, stream>>>(pW, pWsw, 512, 0, 16, 16384);
  xpose_kernel<<<dim3(512), dim3(256), 0, stream>>>(x, xT);
  swz_generic<<<dim3(512), dim3(256), 0, stream>>>(W, W0x, 1024, 0, 16, 131072);
  table_kernel<<<dim3(4, 16), dim3(512), 0, stream>>>(emb, W0x, bias, table);
  hipMemsetAsync(ws + 9437184, 0, 4096, stream);          // prog flags
  hipMemsetAsync(ws + 9961472, 0x01, 4194304, stream);    // rings: LSB=1 rejects first-epoch reads

  persist_kernel<<<dim3(200), dim3(512), 0, stream>>>(
      W0h, W1sw, table, bias + 2048, xT, h0ring, h1ring, flags,
      pWsw, lng, lnb, pb, out);
}

// Round 14
// 2876.425 us; speedup vs baseline: 3.7747x; 1.3674x over previous
//
#include <hip/hip_runtime.h>
#include <hip/hip_bf16.h>

typedef __attribute__((ext_vector_type(8))) short bf16x8;
typedef __attribute__((ext_vector_type(4))) float f32x4;
typedef __attribute__((ext_vector_type(4))) unsigned int u32x4;
typedef unsigned int u32;
typedef unsigned long long u64;
typedef unsigned short u16;

__device__ __forceinline__ short f2bf(float f) {
  __hip_bfloat16 h = __float2bfloat16(f);
  return *reinterpret_cast<short*>(&h);
}
__device__ __forceinline__ float bf2f(u16 s) {
  __hip_bfloat16 h;
  *reinterpret_cast<u16*>(&h) = s;
  return __bfloat162float(h);
}
__device__ __forceinline__ float sigm(float x) { return 1.f / (1.f + __expf(-x)); }

// ---- MALL-coherent transport (R7-proven) ----
__device__ __forceinline__ u32x4 ld128_sys(const void* p) {
  u32x4 r;
  asm volatile("global_load_dwordx4 %0, %1, off sc0 sc1"
               : "=v"(r) : "v"((u64)(uintptr_t)p) : "memory");
  return r;
}
__device__ __forceinline__ void st32_sys(void* p, u32 v) {
  asm volatile("global_store_dword %0, %1, off sc0 sc1"
               :: "v"((u64)(uintptr_t)p), "v"(v) : "memory");
}
__device__ __forceinline__ void vm_drain() {
  asm volatile("s_waitcnt vmcnt(0)" ::: "memory");
  __builtin_amdgcn_sched_barrier(0);
}
__device__ __forceinline__ void vm_wait2() {
  asm volatile("s_waitcnt vmcnt(2)" ::: "memory");
  __builtin_amdgcn_sched_barrier(0);
}
__device__ __forceinline__ u32 ld_flag(const u32* p) {
  return __hip_atomic_load(const_cast<u32*>(p), __ATOMIC_RELAXED, __HIP_MEMORY_SCOPE_AGENT);
}
__device__ __forceinline__ void st_flag(u32* p, u32 v) {
  __hip_atomic_store(p, v, __ATOMIC_RELAXED, __HIP_MEMORY_SCOPE_AGENT);
}
// parity check: all 8 bf16 LSBs in a 16B granule == p?  (pm = p ? 0x00010001 : 0)
__device__ __forceinline__ bool par_ok(u32x4 v, u32 pm) {
  u32 z = ((v[0] ^ pm) | (v[1] ^ pm) | (v[2] ^ pm) | (v[3] ^ pm)) & 0x00010001u;
  return z == 0;
}

// ---------------- precompute kernels ----------------
__global__ void swz_generic(const float* __restrict__ src, short* __restrict__ dst,
                            int row_stride, int col_off, int nks, int nunits) {
  int uid = blockIdx.x * blockDim.x + threadIdx.x;
  if (uid >= nunits) return;
  int lane = uid & 63;
  int rem  = uid >> 6;
  int ks = rem % nks;
  int nf = rem / nks;
  int row = nf * 16 + (lane & 15);
  int k0  = col_off + ks * 32 + (lane >> 4) * 8;
  const float* s = src + (size_t)row * row_stride + k0;
  short v[8];
#pragma unroll
  for (int e = 0; e < 8; ++e) v[e] = f2bf(s[e]);
  *reinterpret_cast<int4*>(dst + (size_t)uid * 8) = *reinterpret_cast<int4*>(v);
}

__global__ void xpose_kernel(const int* __restrict__ x, int* __restrict__ xT) {
  int i = blockIdx.x * blockDim.x + threadIdx.x;   // 131072
  int b = i >> 10, t = i & 1023;
  xT[t * 128 + b] = x[i];
}

__global__ __launch_bounds__(512) void table_kernel(
    const float* __restrict__ emb, const short* __restrict__ Wx,
    const float* __restrict__ b0, float* __restrict__ table) {
  __shared__ __align__(16) char smem[65536];
  const int tid = threadIdx.x;
  const int m0 = blockIdx.x * 64;
  const int nt = blockIdx.y;
  for (int i = tid; i < 4096; i += 512) {
    int row = i >> 6, seg = i & 63;
    const float* sp = emb + (size_t)(m0 + row) * 512 + seg * 8;
    short v[8];
#pragma unroll
    for (int e = 0; e < 8; ++e) v[e] = f2bf(sp[e]);
    *reinterpret_cast<int4*>(smem + row * 1024 + ((seg * 16) ^ ((row & 7) << 4))) =
        *reinterpret_cast<int4*>(v);
  }
  __syncthreads();
  const int w = tid >> 6, lane = tid & 63, l15 = lane & 15, lq = lane >> 4;
  const int mg = (w >> 2) * 32, np = w & 3;
  const char* ap = smem + (mg + l15) * 1024;
  const int swz = (l15 & 7) << 4;
  const int nfbase = nt * 8 + np * 2;
  const short* bp0 = Wx + (size_t)nfbase * 8192 + lane * 8;
  const short* bp1 = bp0 + 8192;
  f32x4 acc[2][2] = {};
#pragma unroll 4
  for (int ks = 0; ks < 16; ++ks) {
    int kb = ks * 64 + lq * 16;
    bf16x8 a0 = *reinterpret_cast<const bf16x8*>(ap + (kb ^ swz));
    bf16x8 a1 = *reinterpret_cast<const bf16x8*>(ap + 16 * 1024 + (kb ^ swz));
    bf16x8 bv0 = *reinterpret_cast<const bf16x8*>(bp0 + ks * 512);
    bf16x8 bv1 = *reinterpret_cast<const bf16x8*>(bp1 + ks * 512);
    acc[0][0] = __builtin_amdgcn_mfma_f32_16x16x32_bf16(a0, bv0, acc[0][0], 0, 0, 0);
    acc[1][0] = __builtin_amdgcn_mfma_f32_16x16x32_bf16(a1, bv0, acc[1][0], 0, 0, 0);
    acc[0][1] = __builtin_amdgcn_mfma_f32_16x16x32_bf16(a0, bv1, acc[0][1], 0, 0, 0);
    acc[1][1] = __builtin_amdgcn_mfma_f32_16x16x32_bf16(a1, bv1, acc[1][1], 0, 0, 0);
  }
#pragma unroll
  for (int mf = 0; mf < 2; ++mf)
#pragma unroll
    for (int nfi = 0; nfi < 2; ++nfi)
#pragma unroll
      for (int r = 0; r < 4; ++r) {
        int ncol = nt * 128 + np * 32 + nfi * 16 + l15;
        int vrow = m0 + mg + mf * 16 + lq * 4 + r;
        table[(size_t)vrow * 2048 + ncol] = acc[mf][nfi][r] + b0[ncol];
      }
}

// ---------------- LSTM role (M_wg = 16 rows) ----------------
// Full B panel held in REGISTERS (loaded once; weights immutable):
//   L0: br0[16]+br1[16] = 128 VGPRs. L1: br[32] = 128 VGPRs.
template<int L>
__device__ void lstm_role(char* smem, int bg, int cs, int tid,
    const short* __restrict__ Wsw, const float* __restrict__ table,
    const float* __restrict__ bias1, const int* __restrict__ xT,
    u16* __restrict__ h0ring, u16* __restrict__ h1ring, u32* __restrict__ FP)
{
  constexpr int NCOL = (L == 0) ? 64 : 32;
  constexpr int NKS  = (L == 0) ? 16 : 32;
  constexpr int ROWB = (L == 0) ? 1024 : 2048;
  const int w = tid >> 6, lane = tid & 63, l15 = lane & 15, lq = lane >> 4;
  const int g = w >> 1;
  const int m0 = bg * 16;
  const int myid = (L == 0) ? (128 + bg * 8 + cs) : (bg * 16 + cs);
  const int nf0 = g * 32 + cs * (NCOL / 16) + (w & 1) * ((L == 0) ? 2 : 1);
  const short* bb0 = Wsw + (size_t)nf0 * (NKS * 512) + lane * 8;
  const short* bb1 = (L == 0) ? bb0 + (size_t)(NKS * 512) : nullptr;
  float* glf = reinterpret_cast<float*>(smem + ((L == 0) ? 16384 : 32768));
  const int swz = (l15 & 7) << 4;
  const bool ew = (L == 0) ? true : (tid < 256);
  const int erow = (L == 0) ? (tid >> 5) : (tid >> 4);
  const int ecp  = (L == 0) ? ((tid & 31) * 2) : ((tid & 15) * 2);
  const int esh  = ((erow >> 2) & 3) * 8;          // gate-exchange rotation
  float c0 = 0.f, c1 = 0.f;
  float2 breg[4];
  if (L == 1 && ew) {
#pragma unroll
    for (int gg = 0; gg < 4; ++gg)
      breg[gg] = *reinterpret_cast<const float2*>(bias1 + gg * 512 + cs * 32 + ecp);
  }
  const int sg = tid & 63;

  // ---- one-time B-panel load into registers ----
  bf16x8 br0[NKS];
  bf16x8 br1[(L == 0) ? 16 : 1];
#pragma unroll
  for (int ks = 0; ks < NKS; ++ks)
    br0[ks] = *reinterpret_cast<const bf16x8*>(bb0 + ks * 512);
  if (L == 0) {
#pragma unroll
    for (int ks = 0; ks < 16; ++ks)
      br1[ks] = *reinterpret_cast<const bf16x8*>(bb1 + ks * 512);
  }

  for (int t = 0; t < 1024; ++t) {
    // ---- backpressure (every 8 ticks, FP only) ----
    if (((t & 7) == 0) && t >= 16) {
      if (w == 0) {
        const u32* a = nullptr;
        if (L == 0) {
          if (lane < 16)      a = &FP[(bg * 16 + lane) * 4];          // L1 consumers of h0
          else if (lane < 24) a = &FP[(128 + bg * 8 + lane - 16) * 4];// L0 peers
        } else {
          if (lane < 16)      a = &FP[(bg * 16 + lane) * 4];          // L1 peers
          else if (lane == 16) a = &FP[(192 + bg) * 4];               // proj
        }
        if (a) { u32 tgt = (u32)(t - 6); while (ld_flag(a) < tgt) __builtin_amdgcn_s_sleep(1); }
      }
    }

    if (L == 0) {
      // ---- stage h0(t-1): parity-validated retry -> bf16 XOR-swizzled LDS ----
      const u32 pm = (((t - 1) >> 4) & 1) ? 0x00010001u : 0u;
      const u16* s0 = h0ring + (size_t)((t + 15) & 15) * 65536 + (size_t)m0 * 512;
      u32x4 v[2];
      const int r0 = tid >> 6, r1 = r0 + 8;
      if (t > 0) {
        v[0] = ld128_sys(s0 + r0 * 512 + sg * 8);
        v[1] = ld128_sys(s0 + r1 * 512 + sg * 8);
        int pend = 3;
        while (pend) {
          vm_drain();
          int np = 0;
          if (pend & 1) {
            if (par_ok(v[0], pm))
              *reinterpret_cast<u32x4*>(smem + r0 * 1024 + ((sg * 16) ^ ((r0 & 7) << 4))) = v[0];
            else { np |= 1; v[0] = ld128_sys(s0 + r0 * 512 + sg * 8); }
          }
          if (pend & 2) {
            if (par_ok(v[1], pm))
              *reinterpret_cast<u32x4*>(smem + r1 * 1024 + ((sg * 16) ^ ((r1 & 7) << 4))) = v[1];
            else { np |= 2; v[1] = ld128_sys(s0 + r1 * 512 + sg * 8); }
          }
          pend = np;
        }
      } else {
        u32x4 z = {0, 0, 0, 0};
        *reinterpret_cast<u32x4*>(smem + r0 * 1024 + ((sg * 16) ^ ((r0 & 7) << 4))) = z;
        *reinterpret_cast<u32x4*>(smem + r1 * 1024 + ((sg * 16) ^ ((r1 & 7) << 4))) = z;
      }
      __syncthreads();                                   // S2: staging ready
      if (tid == 0) st_flag(&FP[myid * 4], (u32)(t + 1));
      // per-thread vocab id + table prefetch (overlaps MFMA)
      int vid = xT[t * 128 + m0 + erow];
      const float* tp = table + (size_t)vid * 2048 + cs * 64 + ecp;
      float2 tbi = *reinterpret_cast<const float2*>(tp);
      float2 tbf = *reinterpret_cast<const float2*>(tp + 512);
      float2 tbo = *reinterpret_cast<const float2*>(tp + 1024);
      float2 tbg = *reinterpret_cast<const float2*>(tp + 1536);
      // ---- MFMA (B entirely from registers) ----
      const char* ap = smem + (size_t)l15 * ROWB;
      f32x4 acc[2][2] = {};
#pragma unroll
      for (int ks = 0; ks < 16; ++ks) {
        bf16x8 a = *reinterpret_cast<const bf16x8*>(ap + ((ks * 64 + lq * 16) ^ swz));
        acc[0][ks & 1] = __builtin_amdgcn_mfma_f32_16x16x32_bf16(a, br0[ks], acc[0][ks & 1], 0, 0, 0);
        acc[1][ks & 1] = __builtin_amdgcn_mfma_f32_16x16x32_bf16(a, br1[ks], acc[1][ks & 1], 0, 0, 0);
      }
      // (no barrier: glf [16K,32K) does not alias staging [0,16K))
#pragma unroll
      for (int nfi = 0; nfi < 2; ++nfi) {
        int col = ((w & 1) * 2 + nfi) * 16 + l15;
#pragma unroll
        for (int r = 0; r < 4; ++r) {
          int lrow = lq * 4 + r;
          glf[(g * 16 + lrow) * 64 + ((col + (lrow >> 2) * 8) & 63)] =
              acc[nfi][0][r] + acc[nfi][1][r];
        }
      }
      __syncthreads();                                   // S4: exchange ready
      // ---- elementwise ----
      int cidx = (ecp + esh) & 63;
      float2 vi = *reinterpret_cast<float2*>(&glf[(0 * 16 + erow) * 64 + cidx]);
      float2 vf = *reinterpret_cast<float2*>(&glf[(1 * 16 + erow) * 64 + cidx]);
      float2 vo = *reinterpret_cast<float2*>(&glf[(2 * 16 + erow) * 64 + cidx]);
      float2 vg = *reinterpret_cast<float2*>(&glf[(3 * 16 + erow) * 64 + cidx]);
      float cv0 = sigm(vf.x + tbf.x) * c0 + sigm(vi.x + tbi.x) * tanhf(vg.x + tbg.x);
      float cv1 = sigm(vf.y + tbf.y) * c1 + sigm(vi.y + tbi.y) * tanhf(vg.y + tbg.y);
      c0 = cv0; c1 = cv1;
      float h0v = sigm(vo.x + tbo.x) * tanhf(cv0);
      float h1v = sigm(vo.y + tbo.y) * tanhf(cv1);
      u32 po = (u32)((t >> 4) & 1);
      u32 pk = (((u32)(u16)f2bf(h0v) & ~1u) | po)
             | ((((u32)(u16)f2bf(h1v) & ~1u) | po) << 16);
      size_t eo = (size_t)(t & 15) * 65536 + (size_t)(m0 + erow) * 512 + cs * 64 + ecp;
      st32_sys(h0ring + eo, pk);
      __syncthreads();                                   // S5: loop end
    } else {
      // ---- L1: issue h0 then h1; validate h0 first; compute h0-half MFMAs
      //      while h1 stores gain visibility time ----
      const u32 pm0 = ((t >> 4) & 1) ? 0x00010001u : 0u;         // h0 epoch t
      const u32 pm1 = (((t - 1) >> 4) & 1) ? 0x00010001u : 0u;   // h1 epoch t-1
      const u16* s0 = h0ring + (size_t)(t & 15) * 65536 + (size_t)m0 * 512;
      const u16* s1 = h1ring + (size_t)((t + 15) & 15) * 65536 + (size_t)m0 * 512;
      const int r0 = tid >> 6, r1 = r0 + 8;
      u32x4 v[4];
      v[0] = ld128_sys(s0 + r0 * 512 + sg * 8);
      v[1] = ld128_sys(s0 + r1 * 512 + sg * 8);
      if (t > 0) {
        v[2] = ld128_sys(s1 + r0 * 512 + sg * 8);
        v[3] = ld128_sys(s1 + r1 * 512 + sg * 8);
      } else {
        u32x4 z = {0, 0, 0, 0};
        *reinterpret_cast<u32x4*>(smem + r0 * 2048 + ((1024 + sg * 16) ^ ((r0 & 7) << 4))) = z;
        *reinterpret_cast<u32x4*>(smem + r1 * 2048 + ((1024 + sg * 16) ^ ((r1 & 7) << 4))) = z;
      }
      if (t > 0) vm_wait2(); else vm_drain();
      {
        int pend = 0;
        if (par_ok(v[0], pm0))
          *reinterpret_cast<u32x4*>(smem + r0 * 2048 + ((sg * 16) ^ ((r0 & 7) << 4))) = v[0];
        else pend |= 1;
        if (par_ok(v[1], pm0))
          *reinterpret_cast<u32x4*>(smem + r1 * 2048 + ((sg * 16) ^ ((r1 & 7) << 4))) = v[1];
        else pend |= 2;
        while (pend) {
          if (pend & 1) v[0] = ld128_sys(s0 + r0 * 512 + sg * 8);
          if (pend & 2) v[1] = ld128_sys(s0 + r1 * 512 + sg * 8);
          vm_drain();
          int np = 0;
          if (pend & 1) {
            if (par_ok(v[0], pm0))
              *reinterpret_cast<u32x4*>(smem + r0 * 2048 + ((sg * 16) ^ ((r0 & 7) << 4))) = v[0];
            else np |= 1;
          }
          if (pend & 2) {
            if (par_ok(v[1], pm0))
              *reinterpret_cast<u32x4*>(smem + r1 * 2048 + ((sg * 16) ^ ((r1 & 7) << 4))) = v[1];
            else np |= 2;
          }
          pend = np;
        }
      }
      __syncthreads();                                   // S2a: h0 staged
      // ---- MFMA h0-half (ks 0..15, B from registers) ----
      const char* ap = smem + (size_t)l15 * ROWB;
      f32x4 acca = {}, accb = {};
#pragma unroll
      for (int ks = 0; ks < 16; ++ks) {
        bf16x8 a = *reinterpret_cast<const bf16x8*>(ap + ((ks * 64 + lq * 16) ^ swz));
        if (ks & 1) accb = __builtin_amdgcn_mfma_f32_16x16x32_bf16(a, br0[ks], accb, 0, 0, 0);
        else        acca = __builtin_amdgcn_mfma_f32_16x16x32_bf16(a, br0[ks], acca, 0, 0, 0);
      }
      // ---- validate h1 (t-1) ----
      if (t > 0) {
        int pend = 0xC;
        while (pend) {
          vm_drain();
          int np = 0;
          if (pend & 4) {
            if (par_ok(v[2], pm1))
              *reinterpret_cast<u32x4*>(smem + r0 * 2048 + ((1024 + sg * 16) ^ ((r0 & 7) << 4))) = v[2];
            else { np |= 4; v[2] = ld128_sys(s1 + r0 * 512 + sg * 8); }
          }
          if (pend & 8) {
            if (par_ok(v[3], pm1))
              *reinterpret_cast<u32x4*>(smem + r1 * 2048 + ((1024 + sg * 16) ^ ((r1 & 7) << 4))) = v[3];
            else { np |= 8; v[3] = ld128_sys(s1 + r1 * 512 + sg * 8); }
          }
          pend = np;
        }
      }
      __syncthreads();                                   // S2b: h1 staged
      if (tid == 0) st_flag(&FP[myid * 4], (u32)(t + 1));
      // ---- MFMA h1-half (ks 16..31, B from registers) ----
#pragma unroll
      for (int ks = 16; ks < 32; ++ks) {
        bf16x8 a = *reinterpret_cast<const bf16x8*>(ap + ((ks * 64 + lq * 16) ^ swz));
        if (ks & 1) accb = __builtin_amdgcn_mfma_f32_16x16x32_bf16(a, br0[ks], accb, 0, 0, 0);
        else        acca = __builtin_amdgcn_mfma_f32_16x16x32_bf16(a, br0[ks], acca, 0, 0, 0);
      }
      // (no barrier: glf [32K,41K) does not alias staging [0,32K))
      {
        int col = (w & 1) * 16 + l15;
#pragma unroll
        for (int r = 0; r < 4; ++r) {
          int lrow = lq * 4 + r;
          glf[(g * 16 + lrow) * 32 + ((col + (lrow >> 2) * 8) & 31)] = acca[r] + accb[r];
        }
      }
      __syncthreads();                                   // S4: exchange ready
      if (ew) {
        int cidx = (ecp + esh) & 31;
        float2 vi = *reinterpret_cast<float2*>(&glf[(0 * 16 + erow) * 32 + cidx]);
        float2 vf = *reinterpret_cast<float2*>(&glf[(1 * 16 + erow) * 32 + cidx]);
        float2 vo = *reinterpret_cast<float2*>(&glf[(2 * 16 + erow) * 32 + cidx]);
        float2 vg = *reinterpret_cast<float2*>(&glf[(3 * 16 + erow) * 32 + cidx]);
        float cv0 = sigm(vf.x + breg[1].x) * c0 + sigm(vi.x + breg[0].x) * tanhf(vg.x + breg[3].x);
        float cv1 = sigm(vf.y + breg[1].y) * c1 + sigm(vi.y + breg[0].y) * tanhf(vg.y + breg[3].y);
        c0 = cv0; c1 = cv1;
        float h0v = sigm(vo.x + breg[2].x) * tanhf(cv0);
        float h1v = sigm(vo.y + breg[2].y) * tanhf(cv1);
        u32 po = (u32)((t >> 4) & 1);
        u32 pk = (((u32)(u16)f2bf(h0v) & ~1u) | po)
               | ((((u32)(u16)f2bf(h1v) & ~1u) | po) << 16);
        size_t eo = (size_t)(t & 15) * 65536 + (size_t)(m0 + erow) * 512 + cs * 32 + ecp;
        st32_sys(h1ring + eo, pk);
      }
      __syncthreads();                                   // S5: loop end
    }
  }
  vm_drain();   // flush final h stores before exit (last consumers still polling)
}

// ---------------- projection role (B in registers too) ----------------
__device__ void proj_role(char* smem, int bg, int tid,
    const u16* __restrict__ h1ring, u32* __restrict__ FP,
    const short* __restrict__ pWswz, const float* __restrict__ lng,
    const float* __restrict__ lnb, const float* __restrict__ pb,
    float* __restrict__ out)
{
  const int w = tid >> 6, lane = tid & 63, l15 = lane & 15, lq = lane >> 4;
  const int m0 = bg * 16;
  const short* bp0 = pWswz + (size_t)(w * 2) * 8192 + lane * 8;
  const short* bp1 = bp0 + 8192;
  const int swzrow = (l15 & 7) << 4;
  float pb0 = pb[(w * 2) * 16 + l15], pb1 = pb[(w * 2 + 1) * 16 + l15];
  const int sg = tid & 63;

  bf16x8 br0[16], br1[16];
#pragma unroll
  for (int ks = 0; ks < 16; ++ks) {
    br0[ks] = *reinterpret_cast<const bf16x8*>(bp0 + ks * 512);
    br1[ks] = *reinterpret_cast<const bf16x8*>(bp1 + ks * 512);
  }

  for (int t = 0; t < 1024; ++t) {
    {
      const u32 pm = ((t >> 4) & 1) ? 0x00010001u : 0u;   // h1 epoch t
      const u16* src = h1ring + (size_t)(t & 15) * 65536 + (size_t)m0 * 512;
      const int r0 = tid >> 6, r1 = r0 + 8;
      u32x4 v[2];
      v[0] = ld128_sys(src + r0 * 512 + sg * 8);
      v[1] = ld128_sys(src + r1 * 512 + sg * 8);
      int pend = 3;
      while (pend) {
        vm_drain();
        int np = 0;
        if (pend & 1) {
          if (par_ok(v[0], pm))
            *reinterpret_cast<u32x4*>(smem + r0 * 1024 + sg * 16) = v[0];
          else { np |= 1; v[0] = ld128_sys(src + r0 * 512 + sg * 8); }
        }
        if (pend & 2) {
          if (par_ok(v[1], pm))
            *reinterpret_cast<u32x4*>(smem + r1 * 1024 + sg * 16) = v[1];
          else { np |= 2; v[1] = ld128_sys(src + r1 * 512 + sg * 8); }
        }
        pend = np;
      }
    }
    __syncthreads();
    if (tid == 0) st_flag(&FP[(192 + bg) * 4], (u32)(t + 1));
    {
      int row = tid >> 5, j = tid & 31;
      const u16* hr = reinterpret_cast<const u16*>(smem) + row * 512;
      float s1 = 0.f, s2 = 0.f;
#pragma unroll
      for (int kk = 0; kk < 16; ++kk) {
        float v = bf2f(hr[j + kk * 32]);
        s1 += v; s2 += v * v;
      }
#pragma unroll
      for (int d = 1; d < 32; d <<= 1) { s1 += __shfl_xor(s1, d, 32); s2 += __shfl_xor(s2, d, 32); }
      float mu = s1 * (1.f / 512.f);
      float rs = rsqrtf(s2 * (1.f / 512.f) - mu * mu + 1e-5f);
      char* zn = smem + 16384;
#pragma unroll
      for (int kk = 0; kk < 16; ++kk) {
        int kcol = j + kk * 32;
        float v = bf2f(hr[kcol]);
        float nv = (v - mu) * rs * lng[kcol] + lnb[kcol];
        *reinterpret_cast<short*>(zn + row * 1024 + ((kcol * 2) ^ ((row & 7) << 4))) = f2bf(nv);
      }
    }
    __syncthreads();
    const char* ap = smem + 16384 + (size_t)l15 * 1024;
    f32x4 acc[2][2] = {};
#pragma unroll
    for (int ks = 0; ks < 16; ++ks) {
      bf16x8 a = *reinterpret_cast<const bf16x8*>(ap + ((ks * 64 + lq * 16) ^ swzrow));
      acc[0][ks & 1] = __builtin_amdgcn_mfma_f32_16x16x32_bf16(a, br0[ks], acc[0][ks & 1], 0, 0, 0);
      acc[1][ks & 1] = __builtin_amdgcn_mfma_f32_16x16x32_bf16(a, br1[ks], acc[1][ks & 1], 0, 0, 0);
    }
#pragma unroll
    for (int nfi = 0; nfi < 2; ++nfi) {
      int vcol = (w * 2 + nfi) * 16 + l15;
      float pbv = nfi ? pb1 : pb0;
#pragma unroll
      for (int r = 0; r < 4; ++r) {
        float vv = acc[nfi][0][r] + acc[nfi][1][r] + pbv;
        out[(size_t)(m0 + lq * 4 + r) * 262144 + (size_t)t * 256 + vcol] = vv;
      }
    }
    __syncthreads();
  }
}

// Grid: 200 blocks. 0..127 = L1, 128..191 = L0, 192..199 = proj.
__global__ __launch_bounds__(512, 1) void persist_kernel(
    const short* __restrict__ W0h, const short* __restrict__ W1,
    const float* __restrict__ table, const float* __restrict__ bias1,
    const int* __restrict__ xT,
    u16* __restrict__ h0ring, u16* __restrict__ h1ring, u32* __restrict__ flags,
    const short* __restrict__ pWswz, const float* __restrict__ lng,
    const float* __restrict__ lnb, const float* __restrict__ pb, float* __restrict__ out)
{
  __shared__ __align__(16) char smem[49408];
  const int bid = blockIdx.x, tid = threadIdx.x;
  if (bid < 128) {
    lstm_role<1>(smem, bid >> 4, bid & 15, tid, W1, nullptr, bias1, xT,
                 h0ring, h1ring, flags);
  } else if (bid < 192) {
    int idx = bid - 128;
    lstm_role<0>(smem, idx >> 3, idx & 7, tid, W0h, table, nullptr, xT,
                 h0ring, h1ring, flags);
  } else {
    proj_role(smem, bid - 192, tid, h1ring, flags, pWswz, lng, lnb, pb, out);
  }
}

extern "C" void kernel_launch(void* const* d_in, const int* in_sizes, int n_in,
                              void* d_out, int out_size, void* d_ws, size_t ws_size,
                              hipStream_t stream) {
  const int*   x    = (const int*)d_in[0];
  const float* emb  = (const float*)d_in[1];
  const float* W    = (const float*)d_in[2];
  const float* bias = (const float*)d_in[3];
  const float* lng  = (const float*)d_in[4];
  const float* lnb  = (const float*)d_in[5];
  const float* pW   = (const float*)d_in[6];
  const float* pb   = (const float*)d_in[7];
  float* out = (float*)d_out;

  char* ws = (char*)d_ws;
  short* W0h   = (short*)(ws + 0);           // 2 MB
  short* W1sw  = (short*)(ws + 2097152);     // 4 MB
  short* pWsw  = (short*)(ws + 6291456);     // 256 KB
  float* table = (float*)(ws + 6815744);     // 2 MB
  int*   xT    = (int*)(ws + 8912896);       // 512 KB
  u32*   flags = (u32*)(ws + 9437184);       // 4 KB (prog)
  u16*   h0ring= (u16*)(ws + 9961472);       // 2 MB: 16 x [128][512] bf16 (parity LSB)
  u16*   h1ring= (u16*)(ws + 12058624);      // 2 MB
  short* W0x   = (short*)(ws + 14155776);    // 2 MB temp (table build)

  swz_generic<<<dim3(512), dim3(256), 0, stream>>>(W, W0h, 1024, 512, 16, 131072);
  swz_generic<<<dim3(1024), dim3(256), 0, stream>>>(W + 2048 * 1024, W1sw, 1024, 0, 32, 262144);
  swz_generic<<<dim3(64), dim3(256), 0, stream>>>(pW, pWsw, 512, 0, 16, 16384);
  xpose_kernel<<<dim3(512), dim3(256), 0, stream>>>(x, xT);
  swz_generic<<<dim3(512), dim3(256), 0, stream>>>(W, W0x, 1024, 0, 16, 131072);
  table_kernel<<<dim3(4, 16), dim3(512), 0, stream>>>(emb, W0x, bias, table);
  hipMemsetAsync(ws + 9437184, 0, 4096, stream);          // prog flags
  hipMemsetAsync(ws + 9961472, 0x01, 4194304, stream);    // rings: LSB=1 rejects first-epoch reads

  persist_kernel<<<dim3(200), dim3(512), 0, stream>>>(
      W0h, W1sw, table, bias + 2048, xT, h0ring, h1ring, flags,
      pWsw, lng, lnb, pb, out);
}